// Round 1
// baseline (5145.264 us; speedup 1.0000x reference)
//
#include <hip/hip_runtime.h>
#include <hip/hip_bf16.h>

constexpr int kB  = 16;     // batch
constexpr int kN  = 512;    // nodes
constexpr int kH  = 256;    // hidden
constexpr int kH4 = 1024;   // 4*H
constexpr int kV  = 32000;  // vocab
constexpr int kS  = 48;     // MAX_STEPS (steps[b] <= 47)

__device__ __forceinline__ float sigm(float x){ return 1.f/(1.f+expf(-x)); }

// ---------------- init: c=h=0, ip[b][0]=1 ----------------
__global__ void k_init(float* c, float* h, float* ip){
  int idx = blockIdx.x*blockDim.x + threadIdx.x;
  int total = kB*kN*kH;
  for (int i = idx; i < total; i += gridDim.x*blockDim.x){ c[i]=0.f; h[i]=0.f; }
  if (idx < kB*kN) ip[idx] = ((idx % kN)==0) ? 1.f : 0.f;
}

// ---------------- CSR build (deterministic): one block per example, 512 threads ----------------
__global__ void k_csr(const int* t_idx, const int* f_idx, int* offsets, int* entries){
  int b = blockIdx.x; int t = threadIdx.x; // t = target node m
  __shared__ int tl[kN], fl[kN], sc[kN];
  tl[t] = t_idx[b*kN+t]; fl[t] = f_idx[b*kN+t];
  __syncthreads();
  int cnt = 0;
  for (int n=0;n<kN;n++) cnt += (tl[n]==t) + (fl[n]==t);
  sc[t] = cnt; __syncthreads();
  // Hillis-Steele inclusive scan over 512 threads
  for (int off=1; off<kN; off<<=1){
    int v = sc[t];
    int add = (t>=off)? sc[t-off] : 0;
    __syncthreads();
    sc[t] = v + add;
    __syncthreads();
  }
  int excl = sc[t] - cnt;
  offsets[b*(kN+1)+t] = excl;
  if (t==0) offsets[b*(kN+1)+kN] = 2*kN;
  int pos = b*2*kN + excl;
  for (int n=0;n<kN;n++) if (tl[n]==t) entries[pos++] = n;            // true-branch sources first
  for (int n=0;n<kN;n++) if (fl[n]==t) entries[pos++] = n | (1<<16);  // then false-branch
}

// ---------------- X = emb @ Wx + bias  (once) ----------------
// grid 512 blocks (16 examples x 32 row-tiles of 16), 256 threads (one output col k per thread)
__global__ __launch_bounds__(256) void k_x(const float* __restrict__ emb,
                                           const float* __restrict__ Wx,
                                           const float* __restrict__ bias,
                                           float* __restrict__ X){
  int t = threadIdx.x;
  int item = blockIdx.x;
  int b = item >> 5; int row0 = (item & 31) * 16;
  __shared__ float as[16][kH];
  for (int i=0;i<16;i++) as[i][t] = emb[(size_t)(b*kN + row0+i)*kH + t];
  __syncthreads();
  float acc[4][16];
  #pragma unroll
  for (int g=0;g<4;g++){
    float bv = bias[g*kH + t];
    #pragma unroll
    for (int r=0;r<16;r++) acc[g][r] = bv;
  }
  for (int kk=0; kk<kH; kk+=4){
    float wv[4][4];
    #pragma unroll
    for (int kkk=0;kkk<4;kkk++)
      #pragma unroll
      for (int g=0;g<4;g++)
        wv[kkk][g] = Wx[(size_t)(kk+kkk)*kH4 + g*kH + t];
    #pragma unroll
    for (int r=0;r<16;r++){
      float4 a4 = *(const float4*)&as[r][kk];
      float av[4] = {a4.x,a4.y,a4.z,a4.w};
      #pragma unroll
      for (int kkk=0;kkk<4;kkk++)
        #pragma unroll
        for (int g=0;g<4;g++)
          acc[g][r] += av[kkk]*wv[kkk][g];
    }
  }
  #pragma unroll
  for (int g=0;g<4;g++)
    #pragma unroll
    for (int r=0;r<16;r++)
      X[(size_t)(b*kN+row0+r)*kH4 + g*kH + t] = acc[g][r];
}

// ---------------- step phase 1: z = X + h@Wh ; gates; exit override; branch softmax; pt/pf ----------------
// grid 512 blocks x 256 threads; dynamic item list over active examples (item = 16-row tile)
__global__ __launch_bounds__(256) void k_step1(
    const float* __restrict__ X, const float* __restrict__ Wh,
    const float* __restrict__ Wb, const float* __restrict__ bbias,
    const int* __restrict__ exit_idx, const int* __restrict__ steps,
    const float* __restrict__ c, const float* __restrict__ h, const float* __restrict__ ip,
    float* __restrict__ c2, float* __restrict__ h2,
    float* __restrict__ pt, float* __restrict__ pf, int s)
{
  int t = threadIdx.x;
  // number of active examples (uniform across grid)
  int nact = 0;
  for (int b=0;b<kB;b++) nact += (s < steps[b]) ? 1 : 0;
  int items = nact * 32;
  // per-thread Wb columns (constant across items)
  float wbc0 = Wb[t*2+0], wbc1 = Wb[t*2+1];
  float wbh0 = Wb[(kH+t)*2+0], wbh1 = Wb[(kH+t)*2+1];

  __shared__ float hs[16][kH];
  __shared__ float red0[16][kH];
  __shared__ float red1[16][kH];

  for (int w = blockIdx.x; w < items; w += gridDim.x){
    // map rank -> example id (uniform scalar loop)
    int rank = w >> 5, b = 0;
    {
      int cntr = 0;
      for (int bb2=0;bb2<kB;bb2++){
        bool a = (s < steps[bb2]);
        if (a && cntr == rank) b = bb2;
        cntr += a ? 1 : 0;
      }
    }
    int row0 = (w & 31) * 16;
    size_t ebase = (size_t)b*kN*kH;
    __syncthreads();
    for (int i=0;i<16;i++) hs[i][t] = h[ebase + (size_t)(row0+i)*kH + t];
    __syncthreads();

    float acc[4][16];
    #pragma unroll
    for (int g=0;g<4;g++)
      #pragma unroll
      for (int r=0;r<16;r++)
        acc[g][r] = X[(size_t)(b*kN+row0+r)*kH4 + g*kH + t];

    for (int kk=0; kk<kH; kk+=4){
      float wv[4][4];
      #pragma unroll
      for (int kkk=0;kkk<4;kkk++)
        #pragma unroll
        for (int g=0;g<4;g++)
          wv[kkk][g] = Wh[(size_t)(kk+kkk)*kH4 + g*kH + t];
      #pragma unroll
      for (int r=0;r<16;r++){
        float4 a4 = *(const float4*)&hs[r][kk];
        float av[4] = {a4.x,a4.y,a4.z,a4.w};
        #pragma unroll
        for (int kkk=0;kkk<4;kkk++)
          #pragma unroll
          for (int g=0;g<4;g++)
            acc[g][r] += av[kkk]*wv[kkk][g];
      }
    }

    int eb = exit_idx[b];
    float pr0[16], pr1[16];
    #pragma unroll
    for (int r=0;r<16;r++){
      int node = row0 + r;
      float iv = sigm(acc[0][r]);
      float fv = sigm(acc[1][r]);
      float gv = tanhf(acc[2][r]);
      float ov = sigm(acc[3][r]);
      float cp = c[ebase + (size_t)node*kH + t];
      float c2v = fv*cp + iv*gv;
      float h2v = ov*tanhf(c2v);
      if (node == eb){ c2v = cp; h2v = hs[r][t]; }
      c2[ebase + (size_t)node*kH + t] = c2v;
      h2[ebase + (size_t)node*kH + t] = h2v;
      pr0[r] = c2v*wbc0 + h2v*wbh0;
      pr1[r] = c2v*wbc1 + h2v*wbh1;
    }
    #pragma unroll
    for (int r=0;r<16;r++){ red0[r][t] = pr0[r]; red1[r][t] = pr1[r]; }
    for (int off=128; off>0; off>>=1){
      __syncthreads();
      if (t < off){
        #pragma unroll
        for (int r=0;r<16;r++){ red0[r][t]+=red0[r][t+off]; red1[r][t]+=red1[r][t+off]; }
      }
    }
    __syncthreads();
    if (t < 16){
      int node = row0 + t;
      float u0 = red0[t][0] + bbias[0];
      float u1 = red1[t][0] + bbias[1];
      float mx = fmaxf(u0,u1);
      float e0 = expf(u0-mx), e1 = expf(u1-mx);
      float inv = 1.f/(e0+e1);
      float ipv = ip[b*kN + node];
      pt[b*kN+node] = (e0*inv)*ipv;
      pf[b*kN+node] = (e1*inv)*ipv;
    }
  }
}

// ---------------- step phase 2: gather via CSR, normalize, write c/h/ip ----------------
// grid 128 blocks (16 examples x 8 chunks of 64 targets), 256 threads (4 waves; wave owns 16 targets)
__global__ __launch_bounds__(256) void k_step2(
    const float* __restrict__ c2, const float* __restrict__ h2,
    const float* __restrict__ pt, const float* __restrict__ pf,
    const int* __restrict__ offsets, const int* __restrict__ entries,
    const int* __restrict__ steps,
    float* __restrict__ c, float* __restrict__ h, float* __restrict__ ip, int s)
{
  int b = blockIdx.x >> 3;
  if (s >= steps[b]) return;
  int chunk = blockIdx.x & 7;
  int wave = threadIdx.x >> 6;
  int lane = threadIdx.x & 63;
  for (int mi = 0; mi < 16; mi++){
    int m = chunk*64 + wave*16 + mi;
    int start = offsets[b*(kN+1)+m], end = offsets[b*(kN+1)+m+1];
    float4 aC = {0.f,0.f,0.f,0.f}, aH = {0.f,0.f,0.f,0.f};
    float aP = 0.f;
    for (int e=start; e<end; ++e){
      int ent = entries[b*2*kN + e];
      int src = ent & 0xFFFF;
      float pv = (ent & (1<<16)) ? pf[b*kN+src] : pt[b*kN+src];
      aP += pv;
      float4 cv = *(const float4*)&c2[(size_t)(b*kN+src)*kH + lane*4];
      float4 hv = *(const float4*)&h2[(size_t)(b*kN+src)*kH + lane*4];
      aC.x += pv*cv.x; aC.y += pv*cv.y; aC.z += pv*cv.z; aC.w += pv*cv.w;
      aH.x += pv*hv.x; aH.y += pv*hv.y; aH.z += pv*hv.z; aH.w += pv*hv.w;
    }
    float inv = 1.f/(aP + 1e-7f);
    float4 oc = {aC.x*inv, aC.y*inv, aC.z*inv, aC.w*inv};
    float4 oh = {aH.x*inv, aH.y*inv, aH.z*inv, aH.w*inv};
    *(float4*)&c[(size_t)(b*kN+m)*kH + lane*4] = oc;
    *(float4*)&h[(size_t)(b*kN+m)*kH + lane*4] = oh;
    if (lane==0) ip[b*kN+m] = aP;
  }
}

// ---------------- final: logits = concat(c[exit], h[exit]) @ Wo + bo ----------------
// grid 125 blocks x 256 threads; thread owns one vocab column for all 16 examples
__global__ __launch_bounds__(256) void k_out(
    const float* __restrict__ c, const float* __restrict__ h,
    const float* __restrict__ Wo, const float* __restrict__ bo,
    const int* __restrict__ exit_idx, float* __restrict__ out)
{
  __shared__ float sf[kB][2*kH];
  int t = threadIdx.x;
  for (int i = t; i < kB*2*kH; i += 256){
    int b = i >> 9; int k = i & 511;
    int e = exit_idx[b];
    sf[b][k] = (k < kH) ? c[(size_t)(b*kN+e)*kH + k] : h[(size_t)(b*kN+e)*kH + (k-kH)];
  }
  __syncthreads();
  int v = blockIdx.x*256 + t;
  if (v < kV){
    float acc[kB];
    float bv = bo[v];
    #pragma unroll
    for (int b=0;b<kB;b++) acc[b] = bv;
    for (int k=0;k<2*kH;k+=4){
      float wv0 = Wo[(size_t)(k+0)*kV + v];
      float wv1 = Wo[(size_t)(k+1)*kV + v];
      float wv2 = Wo[(size_t)(k+2)*kV + v];
      float wv3 = Wo[(size_t)(k+3)*kV + v];
      #pragma unroll
      for (int b=0;b<kB;b++){
        float4 s4 = *(const float4*)&sf[b][k];
        acc[b] += s4.x*wv0 + s4.y*wv1 + s4.z*wv2 + s4.w*wv3;
      }
    }
    #pragma unroll
    for (int b=0;b<kB;b++) out[(size_t)b*kV + v] = acc[b];
  }
}

extern "C" void kernel_launch(void* const* d_in, const int* in_sizes, int n_in,
                              void* d_out, int out_size, void* d_ws, size_t ws_size,
                              hipStream_t stream) {
  const float* emb   = (const float*)d_in[0];
  const float* Wx    = (const float*)d_in[1];
  const float* Wh    = (const float*)d_in[2];
  const float* bias  = (const float*)d_in[3];
  const float* Wb    = (const float*)d_in[4];
  const float* bbias = (const float*)d_in[5];
  const float* Wo    = (const float*)d_in[6];
  const float* bo    = (const float*)d_in[7];
  const int* t_idx   = (const int*)d_in[8];
  const int* f_idx   = (const int*)d_in[9];
  const int* exit_i  = (const int*)d_in[10];
  const int* steps   = (const int*)d_in[11];
  float* out = (float*)d_out;

  char* ws = (char*)d_ws;
  float* X  = (float*)ws; ws += (size_t)kB*kN*kH4*4;
  float* c  = (float*)ws; ws += (size_t)kB*kN*kH*4;
  float* h  = (float*)ws; ws += (size_t)kB*kN*kH*4;
  float* c2 = (float*)ws; ws += (size_t)kB*kN*kH*4;
  float* h2 = (float*)ws; ws += (size_t)kB*kN*kH*4;
  float* ip = (float*)ws; ws += (size_t)kB*kN*4;
  float* pt = (float*)ws; ws += (size_t)kB*kN*4;
  float* pf = (float*)ws; ws += (size_t)kB*kN*4;
  int* offsets = (int*)ws; ws += ((size_t)kB*(kN+1)*4 + 255) & ~(size_t)255;
  int* entries = (int*)ws; ws += (size_t)kB*2*kN*4;

  k_init<<<256, 256, 0, stream>>>(c, h, ip);
  k_csr<<<kB, kN, 0, stream>>>(t_idx, f_idx, offsets, entries);
  k_x<<<512, 256, 0, stream>>>(emb, Wx, bias, X);
  for (int s = 0; s < kS; ++s){
    k_step1<<<512, 256, 0, stream>>>(X, Wh, Wb, bbias, exit_i, steps,
                                     c, h, ip, c2, h2, pt, pf, s);
    k_step2<<<128, 256, 0, stream>>>(c2, h2, pt, pf, offsets, entries, steps,
                                     c, h, ip, s);
  }
  k_out<<<125, 256, 0, stream>>>(c, h, Wo, bo, exit_i, out);
}

// Round 2
// 3016.399 us; speedup vs baseline: 1.7058x; 1.7058x over previous
//
#include <hip/hip_runtime.h>
#include <hip/hip_bf16.h>

constexpr int kB  = 16;     // batch
constexpr int kN  = 512;    // nodes
constexpr int kH  = 256;    // hidden
constexpr int kH4 = 1024;   // 4*H
constexpr int kV  = 32000;  // vocab
constexpr int kS  = 48;     // MAX_STEPS (steps[b] <= 47)

typedef __attribute__((ext_vector_type(8))) short short8v;  // 8 bf16 = 4 VGPR
typedef __attribute__((ext_vector_type(4))) float f32x4;

__device__ __forceinline__ float sigm(float x){ return 1.f/(1.f+expf(-x)); }

__device__ __forceinline__ unsigned short f2bf(float f){
  __hip_bfloat16 h = __float2bfloat16(f);
  return __builtin_bit_cast(unsigned short, h);
}
__device__ __forceinline__ float bf2f(unsigned short u){
  __hip_bfloat16 h = __builtin_bit_cast(__hip_bfloat16, u);
  return __bfloat162float(h);
}

// ---------------- init: c=0, h_hi=h_lo=0, ip[b][0]=1 ----------------
__global__ void k_init(float* c, float* ip, unsigned short* h_hi, unsigned short* h_lo){
  int idx = blockIdx.x*blockDim.x + threadIdx.x;
  int total = kB*kN*kH;
  for (int i = idx; i < total; i += gridDim.x*blockDim.x){
    c[i]=0.f; h_hi[i]=0; h_lo[i]=0;
  }
  if (idx < kB*kN) ip[idx] = ((idx % kN)==0) ? 1.f : 0.f;
}

// ---------------- CSR build (deterministic): one block per example, 512 threads ----------------
__global__ void k_csr(const int* t_idx, const int* f_idx, int* offsets, int* entries){
  int b = blockIdx.x; int t = threadIdx.x; // t = target node m
  __shared__ int tl[kN], fl[kN], sc[kN];
  tl[t] = t_idx[b*kN+t]; fl[t] = f_idx[b*kN+t];
  __syncthreads();
  int cnt = 0;
  for (int n=0;n<kN;n++) cnt += (tl[n]==t) + (fl[n]==t);
  sc[t] = cnt; __syncthreads();
  for (int off=1; off<kN; off<<=1){
    int v = sc[t];
    int add = (t>=off)? sc[t-off] : 0;
    __syncthreads();
    sc[t] = v + add;
    __syncthreads();
  }
  int excl = sc[t] - cnt;
  offsets[b*(kN+1)+t] = excl;
  if (t==0) offsets[b*(kN+1)+kN] = 2*kN;
  int pos = b*2*kN + excl;
  for (int n=0;n<kN;n++) if (tl[n]==t) entries[pos++] = n;            // true first
  for (int n=0;n<kN;n++) if (fl[n]==t) entries[pos++] = n | (1<<16);  // then false
}

// ---------------- pack Wh into MFMA B-fragment order, split hi/lo bf16 ----------------
// frag fi = ((kt*4 + wn)*16 + (g*4+j)); lane l supplies B[k][col] for
// k = kt*32 + (l>>4)*8 + jj, col = g*256 + wn*64 + j*16 + (l&15)
__global__ void k_pack(const float* __restrict__ Wh, unsigned short* __restrict__ ph,
                       unsigned short* __restrict__ pl){
  int fi = blockIdx.x; int l = threadIdx.x; // 64 threads
  int kt = fi >> 6; int wn = (fi>>4)&3; int cfl = fi & 15;
  int g = cfl>>2; int j = cfl&3;
  int col = g*kH + wn*64 + j*16 + (l&15);
  int kb = kt*32 + (l>>4)*8;
  size_t o = (size_t)fi*512 + (size_t)l*8;
  #pragma unroll
  for (int jj=0; jj<8; ++jj){
    float w = Wh[(size_t)(kb+jj)*kH4 + col];
    unsigned short hi = f2bf(w);
    unsigned short lo = f2bf(w - bf2f(hi));
    ph[o+jj] = hi; pl[o+jj] = lo;
  }
}

// ---------------- X = emb @ Wx + bias  (once) ----------------
__global__ __launch_bounds__(256) void k_x(const float* __restrict__ emb,
                                           const float* __restrict__ Wx,
                                           const float* __restrict__ bias,
                                           float* __restrict__ X){
  int t = threadIdx.x;
  int item = blockIdx.x;
  int b = item >> 5; int row0 = (item & 31) * 16;
  __shared__ float as[16][kH];
  for (int i=0;i<16;i++) as[i][t] = emb[(size_t)(b*kN + row0+i)*kH + t];
  __syncthreads();
  float acc[4][16];
  #pragma unroll
  for (int g=0;g<4;g++){
    float bv = bias[g*kH + t];
    #pragma unroll
    for (int r=0;r<16;r++) acc[g][r] = bv;
  }
  for (int kk=0; kk<kH; kk+=4){
    float wv[4][4];
    #pragma unroll
    for (int kkk=0;kkk<4;kkk++)
      #pragma unroll
      for (int g=0;g<4;g++)
        wv[kkk][g] = Wx[(size_t)(kk+kkk)*kH4 + g*kH + t];
    #pragma unroll
    for (int r=0;r<16;r++){
      float4 a4 = *(const float4*)&as[r][kk];
      float av[4] = {a4.x,a4.y,a4.z,a4.w};
      #pragma unroll
      for (int kkk=0;kkk<4;kkk++)
        #pragma unroll
        for (int g=0;g<4;g++)
          acc[g][r] += av[kkk]*wv[kkk][g];
    }
  }
  #pragma unroll
  for (int g=0;g<4;g++)
    #pragma unroll
    for (int r=0;r<16;r++)
      X[(size_t)(b*kN+row0+r)*kH4 + g*kH + t] = acc[g][r];
}

// ---------------- step phase 1 (MFMA): z = X + h@Wh ; gates; exit; branch softmax ----------------
// grid 256 blocks (16 ex x 16 rowblocks of 32), 256 threads = 4 waves (wave = 64-channel group)
__global__ __launch_bounds__(256) void k_step1(
    const float* __restrict__ X,
    const unsigned short* __restrict__ Wp_hi, const unsigned short* __restrict__ Wp_lo,
    const unsigned short* __restrict__ h_hi, const unsigned short* __restrict__ h_lo,
    const float* __restrict__ Wb, const float* __restrict__ bbias,
    const int* __restrict__ exit_idx, const int* __restrict__ steps,
    const float* __restrict__ c, const float* __restrict__ ip,
    float* __restrict__ c2, float* __restrict__ h2,
    float* __restrict__ pt, float* __restrict__ pf, int s)
{
  int b = blockIdx.x >> 4;
  if (s >= steps[b]) return;
  int row0 = (blockIdx.x & 15) * 32;
  int tid = threadIdx.x;
  int wn = tid >> 6;          // wave id: owns channels [wn*64, wn*64+64)
  int lane = tid & 63;
  int lrow = lane & 15, lk = lane >> 4;

  // ---- accumulators init from X ----
  f32x4 acc[2][4][4];  // [rowfrag][gate][j]
  {
    const float* Xb = X + (size_t)b*kN*kH4;
    #pragma unroll
    for (int r=0;r<2;r++)
      #pragma unroll
      for (int g=0;g<4;g++)
        #pragma unroll
        for (int j=0;j<4;j++){
          int col = g*kH + wn*64 + j*16 + lrow;
          int rbase = row0 + r*16 + lk*4;
          #pragma unroll
          for (int reg=0;reg<4;reg++)
            acc[r][g][j][reg] = Xb[(size_t)(rbase+reg)*kH4 + col];
        }
  }

  // ---- K-loop: 8 iters of K=32; 3-term split-bf16 ----
  const unsigned short* hh = h_hi + ((size_t)b*kN + row0)*kH;
  const unsigned short* hl = h_lo + ((size_t)b*kN + row0)*kH;
  for (int kt=0; kt<8; ++kt){
    short8v a_hi[2], a_lo[2];
    #pragma unroll
    for (int r=0;r<2;r++){
      size_t off = (size_t)(r*16+lrow)*kH + kt*32 + lk*8;
      a_hi[r] = *(const short8v*)(hh + off);
      a_lo[r] = *(const short8v*)(hl + off);
    }
    #pragma unroll
    for (int cf=0; cf<16; ++cf){
      size_t fb = ((size_t)((kt*4+wn)*16+cf))*512 + (size_t)lane*8;
      short8v bh = *(const short8v*)(Wp_hi+fb);
      short8v bl = *(const short8v*)(Wp_lo+fb);
      int g = cf>>2, j = cf&3;
      #pragma unroll
      for (int r=0;r<2;r++){
        acc[r][g][j] = __builtin_amdgcn_mfma_f32_16x16x32_bf16(a_hi[r], bh, acc[r][g][j], 0,0,0);
        acc[r][g][j] = __builtin_amdgcn_mfma_f32_16x16x32_bf16(a_lo[r], bh, acc[r][g][j], 0,0,0);
        acc[r][g][j] = __builtin_amdgcn_mfma_f32_16x16x32_bf16(a_hi[r], bl, acc[r][g][j], 0,0,0);
      }
    }
  }

  // ---- epilogue: gates, exit override, branch-logit partials ----
  int eb = exit_idx[b];
  float wbc0[4], wbc1[4], wbh0[4], wbh1[4];
  #pragma unroll
  for (int j=0;j<4;j++){
    int t = wn*64 + j*16 + lrow;
    wbc0[j] = Wb[t*2+0];      wbc1[j] = Wb[t*2+1];
    wbh0[j] = Wb[(kH+t)*2+0]; wbh1[j] = Wb[(kH+t)*2+1];
  }
  float pr0[8], pr1[8];
  #pragma unroll
  for (int i=0;i<8;i++){ pr0[i]=0.f; pr1[i]=0.f; }

  #pragma unroll
  for (int r=0;r<2;r++)
    #pragma unroll
    for (int reg=0;reg<4;reg++){
      int row = row0 + r*16 + lk*4 + reg;
      size_t rb = ((size_t)b*kN + row)*kH;
      bool isExit = (row == eb);
      #pragma unroll
      for (int j=0;j<4;j++){
        int t = wn*64 + j*16 + lrow;
        float zi = acc[r][0][j][reg];
        float zf = acc[r][1][j][reg];
        float zg = acc[r][2][j][reg];
        float zo = acc[r][3][j][reg];
        float cp = c[rb + t];
        float c2v = sigm(zf)*cp + sigm(zi)*tanhf(zg);
        float h2v = sigm(zo)*tanhf(c2v);
        if (isExit){
          c2v = cp;
          h2v = bf2f(h_hi[rb+t]) + bf2f(h_lo[rb+t]);
        }
        c2[rb+t] = c2v;
        h2[rb+t] = h2v;
        int pi = r*4+reg;
        pr0[pi] += c2v*wbc0[j] + h2v*wbh0[j];
        pr1[pi] += c2v*wbc1[j] + h2v*wbh1[j];
      }
    }

  // reduce across the 16 t-lanes (lrow)
  #pragma unroll
  for (int off=1; off<16; off<<=1){
    #pragma unroll
    for (int i=0;i<8;i++){
      pr0[i] += __shfl_xor(pr0[i], off);
      pr1[i] += __shfl_xor(pr1[i], off);
    }
  }
  __shared__ float prs[4][32][2];
  if (lrow == 0){
    #pragma unroll
    for (int r=0;r<2;r++)
      #pragma unroll
      for (int reg=0;reg<4;reg++){
        int lr = r*16 + lk*4 + reg;
        prs[wn][lr][0] = pr0[r*4+reg];
        prs[wn][lr][1] = pr1[r*4+reg];
      }
  }
  __syncthreads();
  if (tid < 32){
    int row = row0 + tid;
    float u0 = bbias[0], u1 = bbias[1];
    #pragma unroll
    for (int w=0;w<4;w++){ u0 += prs[w][tid][0]; u1 += prs[w][tid][1]; }
    float mx = fmaxf(u0,u1);
    float e0 = expf(u0-mx), e1 = expf(u1-mx);
    float inv = 1.f/(e0+e1);
    float ipv = ip[b*kN + row];
    pt[b*kN+row] = (e0*inv)*ipv;
    pf[b*kN+row] = (e1*inv)*ipv;
  }
}

// ---------------- step phase 2: gather via CSR, normalize, write c (f32) + h (hi/lo bf16), ip ----------------
__global__ __launch_bounds__(256) void k_step2(
    const float* __restrict__ c2, const float* __restrict__ h2,
    const float* __restrict__ pt, const float* __restrict__ pf,
    const int* __restrict__ offsets, const int* __restrict__ entries,
    const int* __restrict__ steps,
    float* __restrict__ c, unsigned short* __restrict__ h_hi, unsigned short* __restrict__ h_lo,
    float* __restrict__ ip, int s)
{
  int b = blockIdx.x >> 3;
  if (s >= steps[b]) return;
  int chunk = blockIdx.x & 7;
  int wave = threadIdx.x >> 6;
  int lane = threadIdx.x & 63;
  for (int mi = 0; mi < 16; mi++){
    int m = chunk*64 + wave*16 + mi;
    int start = offsets[b*(kN+1)+m], end = offsets[b*(kN+1)+m+1];
    float4 aC = {0.f,0.f,0.f,0.f}, aH = {0.f,0.f,0.f,0.f};
    float aP = 0.f;
    for (int e=start; e<end; ++e){
      int ent = entries[b*2*kN + e];
      int src = ent & 0xFFFF;
      float pv = (ent & (1<<16)) ? pf[b*kN+src] : pt[b*kN+src];
      aP += pv;
      float4 cv = *(const float4*)&c2[(size_t)(b*kN+src)*kH + lane*4];
      float4 hv = *(const float4*)&h2[(size_t)(b*kN+src)*kH + lane*4];
      aC.x += pv*cv.x; aC.y += pv*cv.y; aC.z += pv*cv.z; aC.w += pv*cv.w;
      aH.x += pv*hv.x; aH.y += pv*hv.y; aH.z += pv*hv.z; aH.w += pv*hv.w;
    }
    float inv = 1.f/(aP + 1e-7f);
    float oc[4] = {aC.x*inv, aC.y*inv, aC.z*inv, aC.w*inv};
    float oh[4] = {aH.x*inv, aH.y*inv, aH.z*inv, aH.w*inv};
    size_t base = (size_t)(b*kN+m)*kH + lane*4;
    *(float4*)&c[base] = *(float4*)oc;
    ushort4 hh4, hl4;
    unsigned short* hhp = (unsigned short*)&hh4;
    unsigned short* hlp = (unsigned short*)&hl4;
    #pragma unroll
    for (int q=0;q<4;q++){
      unsigned short hi = f2bf(oh[q]);
      hhp[q] = hi;
      hlp[q] = f2bf(oh[q] - bf2f(hi));
    }
    *(ushort4*)&h_hi[base] = hh4;
    *(ushort4*)&h_lo[base] = hl4;
    if (lane==0) ip[b*kN+m] = aP;
  }
}

// ---------------- final: logits = concat(c[exit], h[exit]) @ Wo + bo ----------------
__global__ __launch_bounds__(256) void k_out(
    const float* __restrict__ c,
    const unsigned short* __restrict__ h_hi, const unsigned short* __restrict__ h_lo,
    const float* __restrict__ Wo, const float* __restrict__ bo,
    const int* __restrict__ exit_idx, float* __restrict__ out)
{
  __shared__ float sf[kB][2*kH];
  int t = threadIdx.x;
  for (int i = t; i < kB*2*kH; i += 256){
    int b = i >> 9; int k = i & 511;
    int e = exit_idx[b];
    size_t base = (size_t)(b*kN+e)*kH;
    sf[b][k] = (k < kH) ? c[base + k]
                        : bf2f(h_hi[base + (k-kH)]) + bf2f(h_lo[base + (k-kH)]);
  }
  __syncthreads();
  int v = blockIdx.x*256 + t;
  if (v < kV){
    float acc[kB];
    float bv = bo[v];
    #pragma unroll
    for (int b=0;b<kB;b++) acc[b] = bv;
    for (int k=0;k<2*kH;k+=4){
      float wv0 = Wo[(size_t)(k+0)*kV + v];
      float wv1 = Wo[(size_t)(k+1)*kV + v];
      float wv2 = Wo[(size_t)(k+2)*kV + v];
      float wv3 = Wo[(size_t)(k+3)*kV + v];
      #pragma unroll
      for (int b=0;b<kB;b++){
        float4 s4 = *(const float4*)&sf[b][k];
        acc[b] += s4.x*wv0 + s4.y*wv1 + s4.z*wv2 + s4.w*wv3;
      }
    }
    #pragma unroll
    for (int b=0;b<kB;b++) out[(size_t)b*kV + v] = acc[b];
  }
}

extern "C" void kernel_launch(void* const* d_in, const int* in_sizes, int n_in,
                              void* d_out, int out_size, void* d_ws, size_t ws_size,
                              hipStream_t stream) {
  const float* emb   = (const float*)d_in[0];
  const float* Wx    = (const float*)d_in[1];
  const float* Wh    = (const float*)d_in[2];
  const float* bias  = (const float*)d_in[3];
  const float* Wb    = (const float*)d_in[4];
  const float* bbias = (const float*)d_in[5];
  const float* Wo    = (const float*)d_in[6];
  const float* bo    = (const float*)d_in[7];
  const int* t_idx   = (const int*)d_in[8];
  const int* f_idx   = (const int*)d_in[9];
  const int* exit_i  = (const int*)d_in[10];
  const int* steps   = (const int*)d_in[11];
  float* out = (float*)d_out;

  char* ws = (char*)d_ws;
  float* X  = (float*)ws; ws += (size_t)kB*kN*kH4*4;
  float* c  = (float*)ws; ws += (size_t)kB*kN*kH*4;
  float* c2 = (float*)ws; ws += (size_t)kB*kN*kH*4;
  float* h2 = (float*)ws; ws += (size_t)kB*kN*kH*4;
  unsigned short* h_hi = (unsigned short*)ws; ws += (size_t)kB*kN*kH*2;
  unsigned short* h_lo = (unsigned short*)ws; ws += (size_t)kB*kN*kH*2;
  unsigned short* Wp_hi = (unsigned short*)ws; ws += (size_t)kH*kH4*2;
  unsigned short* Wp_lo = (unsigned short*)ws; ws += (size_t)kH*kH4*2;
  float* ip = (float*)ws; ws += (size_t)kB*kN*4;
  float* pt = (float*)ws; ws += (size_t)kB*kN*4;
  float* pf = (float*)ws; ws += (size_t)kB*kN*4;
  int* offsets = (int*)ws; ws += ((size_t)kB*(kN+1)*4 + 255) & ~(size_t)255;
  int* entries = (int*)ws; ws += (size_t)kB*2*kN*4;

  k_init<<<256, 256, 0, stream>>>(c, ip, h_hi, h_lo);
  k_csr<<<kB, kN, 0, stream>>>(t_idx, f_idx, offsets, entries);
  k_pack<<<512, 64, 0, stream>>>(Wh, Wp_hi, Wp_lo);
  k_x<<<512, 256, 0, stream>>>(emb, Wx, bias, X);
  for (int s = 0; s < kS; ++s){
    k_step1<<<256, 256, 0, stream>>>(X, Wp_hi, Wp_lo, h_hi, h_lo, Wb, bbias,
                                     exit_i, steps, c, ip, c2, h2, pt, pf, s);
    k_step2<<<128, 256, 0, stream>>>(c2, h2, pt, pf, offsets, entries, steps,
                                     c, h_hi, h_lo, ip, s);
  }
  k_out<<<125, 256, 0, stream>>>(c, h_hi, h_lo, Wo, bo, exit_i, out);
}

// Round 3
// 2132.058 us; speedup vs baseline: 2.4133x; 1.4148x over previous
//
#include <hip/hip_runtime.h>
#include <hip/hip_bf16.h>

constexpr int kB  = 16;     // batch
constexpr int kN  = 512;    // nodes
constexpr int kH  = 256;    // hidden
constexpr int kH4 = 1024;   // 4*H
constexpr int kV  = 32000;  // vocab
constexpr int kS  = 48;     // MAX_STEPS (steps[b] <= 47)

typedef __attribute__((ext_vector_type(8))) short short8v;  // 8 bf16 = 4 VGPR
typedef __attribute__((ext_vector_type(4))) float f32x4;

__device__ __forceinline__ float sigm(float x){ return 1.f/(1.f+expf(-x)); }

__device__ __forceinline__ unsigned short f2bf(float f){
  __hip_bfloat16 h = __float2bfloat16(f);
  return __builtin_bit_cast(unsigned short, h);
}
__device__ __forceinline__ float bf2f(unsigned short u){
  __hip_bfloat16 h = __builtin_bit_cast(__hip_bfloat16, u);
  return __bfloat162float(h);
}

// ---------------- init: c=0, h_hi=h_lo=0, ip[b][0]=1 ----------------
__global__ void k_init(float* c, float* ip, unsigned short* h_hi, unsigned short* h_lo){
  int idx = blockIdx.x*blockDim.x + threadIdx.x;
  int total = kB*kN*kH;
  for (int i = idx; i < total; i += gridDim.x*blockDim.x){
    c[i]=0.f; h_hi[i]=0; h_lo[i]=0;
  }
  if (idx < kB*kN) ip[idx] = ((idx % kN)==0) ? 1.f : 0.f;
}

// ---------------- CSR build (deterministic): one block per example, 512 threads ----------------
__global__ void k_csr(const int* t_idx, const int* f_idx, int* offsets, int* entries){
  int b = blockIdx.x; int t = threadIdx.x; // t = target node m
  __shared__ int tl[kN], fl[kN], sc[kN];
  tl[t] = t_idx[b*kN+t]; fl[t] = f_idx[b*kN+t];
  __syncthreads();
  int cnt = 0;
  for (int n=0;n<kN;n++) cnt += (tl[n]==t) + (fl[n]==t);
  sc[t] = cnt; __syncthreads();
  for (int off=1; off<kN; off<<=1){
    int v = sc[t];
    int add = (t>=off)? sc[t-off] : 0;
    __syncthreads();
    sc[t] = v + add;
    __syncthreads();
  }
  int excl = sc[t] - cnt;
  offsets[b*(kN+1)+t] = excl;
  if (t==0) offsets[b*(kN+1)+kN] = 2*kN;
  int pos = b*2*kN + excl;
  for (int n=0;n<kN;n++) if (tl[n]==t) entries[pos++] = n;            // true first
  for (int n=0;n<kN;n++) if (fl[n]==t) entries[pos++] = n | (1<<16);  // then false
}

// ---------------- pack Wh into MFMA B-fragment order, split hi/lo bf16 ----------------
// frag fi = ((kt*4 + wo)*16 + (g*4+j)); lane l supplies B[k][col] for
// k = kt*32 + (l>>4)*8 + jj, col = g*256 + wo*64 + j*16 + (l&15)
__global__ void k_pack(const float* __restrict__ Wh, unsigned short* __restrict__ ph,
                       unsigned short* __restrict__ pl){
  int fi = blockIdx.x; int l = threadIdx.x; // 64 threads
  int kt = fi >> 6; int wo = (fi>>4)&3; int cfl = fi & 15;
  int g = cfl>>2; int j = cfl&3;
  int col = g*kH + wo*64 + j*16 + (l&15);
  int kb = kt*32 + (l>>4)*8;
  size_t o = (size_t)fi*512 + (size_t)l*8;
  #pragma unroll
  for (int jj=0; jj<8; ++jj){
    float w = Wh[(size_t)(kb+jj)*kH4 + col];
    unsigned short hi = f2bf(w);
    unsigned short lo = f2bf(w - bf2f(hi));
    ph[o+jj] = hi; pl[o+jj] = lo;
  }
}

// ---------------- X = emb @ Wx + bias  (once) ----------------
__global__ __launch_bounds__(256) void k_x(const float* __restrict__ emb,
                                           const float* __restrict__ Wx,
                                           const float* __restrict__ bias,
                                           float* __restrict__ X){
  int t = threadIdx.x;
  int item = blockIdx.x;
  int b = item >> 5; int row0 = (item & 31) * 16;
  __shared__ float as[16][kH];
  for (int i=0;i<16;i++) as[i][t] = emb[(size_t)(b*kN + row0+i)*kH + t];
  __syncthreads();
  float acc[4][16];
  #pragma unroll
  for (int g=0;g<4;g++){
    float bv = bias[g*kH + t];
    #pragma unroll
    for (int r=0;r<16;r++) acc[g][r] = bv;
  }
  for (int kk=0; kk<kH; kk+=4){
    float wv[4][4];
    #pragma unroll
    for (int kkk=0;kkk<4;kkk++)
      #pragma unroll
      for (int g=0;g<4;g++)
        wv[kkk][g] = Wx[(size_t)(kk+kkk)*kH4 + g*kH + t];
    #pragma unroll
    for (int r=0;r<16;r++){
      float4 a4 = *(const float4*)&as[r][kk];
      float av[4] = {a4.x,a4.y,a4.z,a4.w};
      #pragma unroll
      for (int kkk=0;kkk<4;kkk++)
        #pragma unroll
        for (int g=0;g<4;g++)
          acc[g][r] += av[kkk]*wv[kkk][g];
    }
  }
  #pragma unroll
  for (int g=0;g<4;g++)
    #pragma unroll
    for (int r=0;r<16;r++)
      X[(size_t)(b*kN+row0+r)*kH4 + g*kH + t] = acc[g][r];
}

// ---------------- step phase 1 (MFMA, 16 waves/block): z = X + h@Wh ; gates; exit; softmax ----------------
// grid 256 blocks (16 ex x 16 rowblocks of 32), 1024 threads = 16 waves.
// wave wn owns channel group [wn*16, wn*16+16) for all 4 gates; 2 row-frags (32 rows).
__global__ __launch_bounds__(1024) void k_step1(
    const float* __restrict__ X,
    const unsigned short* __restrict__ Wp_hi, const unsigned short* __restrict__ Wp_lo,
    const unsigned short* __restrict__ h_hi, const unsigned short* __restrict__ h_lo,
    const float* __restrict__ Wb, const float* __restrict__ bbias,
    const int* __restrict__ exit_idx, const int* __restrict__ steps,
    const float* __restrict__ c, const float* __restrict__ ip,
    float* __restrict__ c2, float* __restrict__ h2,
    float* __restrict__ pt, float* __restrict__ pf, int s)
{
  int b = blockIdx.x >> 4;
  if (s >= steps[b]) return;
  int row0 = (blockIdx.x & 15) * 32;
  int tid = threadIdx.x;
  int wn = tid >> 6;          // 0..15: channel group
  int lane = tid & 63;
  int lrow = lane & 15, lk = lane >> 4;
  int ch = wn*16 + lrow;      // this lane's channel

  // ---- accumulators init from X: acc[rf][gate] ----
  f32x4 acc[2][4];
  {
    const float* Xb = X + (size_t)b*kN*kH4;
    #pragma unroll
    for (int r=0;r<2;r++)
      #pragma unroll
      for (int g=0;g<4;g++){
        int col = g*kH + ch;
        int rbase = row0 + r*16 + lk*4;
        #pragma unroll
        for (int reg=0;reg<4;reg++)
          acc[r][g][reg] = Xb[(size_t)(rbase+reg)*kH4 + col];
      }
  }

  // ---- K-loop: 8 iters of K=32; 3-term split-bf16 ----
  const unsigned short* hh = h_hi + ((size_t)b*kN + row0)*kH;
  const unsigned short* hl = h_lo + ((size_t)b*kN + row0)*kH;
  int wo = wn >> 2, jj4 = wn & 3;
  for (int kt=0; kt<8; ++kt){
    short8v a_hi[2], a_lo[2];
    #pragma unroll
    for (int r=0;r<2;r++){
      size_t off = (size_t)(r*16+lrow)*kH + kt*32 + lk*8;
      a_hi[r] = *(const short8v*)(hh + off);
      a_lo[r] = *(const short8v*)(hl + off);
    }
    #pragma unroll
    for (int g=0; g<4; ++g){
      size_t fb = ((size_t)((kt*4+wo)*16 + g*4 + jj4))*512 + (size_t)lane*8;
      short8v bh = *(const short8v*)(Wp_hi+fb);
      short8v bl = *(const short8v*)(Wp_lo+fb);
      #pragma unroll
      for (int r=0;r<2;r++){
        acc[r][g] = __builtin_amdgcn_mfma_f32_16x16x32_bf16(a_hi[r], bh, acc[r][g], 0,0,0);
        acc[r][g] = __builtin_amdgcn_mfma_f32_16x16x32_bf16(a_lo[r], bh, acc[r][g], 0,0,0);
        acc[r][g] = __builtin_amdgcn_mfma_f32_16x16x32_bf16(a_hi[r], bl, acc[r][g], 0,0,0);
      }
    }
  }

  // ---- epilogue: gates, exit override, branch-logit partials ----
  int eb = exit_idx[b];
  float wbc0 = Wb[ch*2+0],      wbc1 = Wb[ch*2+1];
  float wbh0 = Wb[(kH+ch)*2+0], wbh1 = Wb[(kH+ch)*2+1];
  float pr0[8], pr1[8];

  #pragma unroll
  for (int r=0;r<2;r++)
    #pragma unroll
    for (int reg=0;reg<4;reg++){
      int row = row0 + r*16 + lk*4 + reg;
      size_t rb = ((size_t)b*kN + row)*kH;
      float zi = acc[r][0][reg];
      float zf = acc[r][1][reg];
      float zg = acc[r][2][reg];
      float zo = acc[r][3][reg];
      float cp = c[rb + ch];
      float c2v = sigm(zf)*cp + sigm(zi)*tanhf(zg);
      float h2v = sigm(zo)*tanhf(c2v);
      if (row == eb){
        c2v = cp;
        h2v = bf2f(h_hi[rb+ch]) + bf2f(h_lo[rb+ch]);
      }
      c2[rb+ch] = c2v;
      h2[rb+ch] = h2v;
      int pi = r*4+reg;
      pr0[pi] = c2v*wbc0 + h2v*wbh0;
      pr1[pi] = c2v*wbc1 + h2v*wbh1;
    }

  // reduce across the 16 lrow lanes (channels within the wave's group)
  #pragma unroll
  for (int off=1; off<16; off<<=1){
    #pragma unroll
    for (int i=0;i<8;i++){
      pr0[i] += __shfl_xor(pr0[i], off);
      pr1[i] += __shfl_xor(pr1[i], off);
    }
  }
  __shared__ float prs[16][32][2];
  if (lrow == 0){
    #pragma unroll
    for (int r=0;r<2;r++)
      #pragma unroll
      for (int reg=0;reg<4;reg++){
        int lr = r*16 + lk*4 + reg;
        prs[wn][lr][0] = pr0[r*4+reg];
        prs[wn][lr][1] = pr1[r*4+reg];
      }
  }
  __syncthreads();
  if (tid < 32){
    int row = row0 + tid;
    float u0 = bbias[0], u1 = bbias[1];
    #pragma unroll
    for (int w=0;w<16;w++){ u0 += prs[w][tid][0]; u1 += prs[w][tid][1]; }
    float mx = fmaxf(u0,u1);
    float e0 = expf(u0-mx), e1 = expf(u1-mx);
    float inv = 1.f/(e0+e1);
    float ipv = ip[b*kN + row];
    pt[b*kN+row] = (e0*inv)*ipv;
    pf[b*kN+row] = (e1*inv)*ipv;
  }
}

// ---------------- step phase 2: gather via CSR, normalize, write c (f32) + h (hi/lo bf16), ip ----------------
// grid 1024 blocks (16 ex x 64 chunks of 8 targets), 256 threads; wave handles 2 targets
__global__ __launch_bounds__(256) void k_step2(
    const float* __restrict__ c2, const float* __restrict__ h2,
    const float* __restrict__ pt, const float* __restrict__ pf,
    const int* __restrict__ offsets, const int* __restrict__ entries,
    const int* __restrict__ steps,
    float* __restrict__ c, unsigned short* __restrict__ h_hi, unsigned short* __restrict__ h_lo,
    float* __restrict__ ip, int s)
{
  int b = blockIdx.x >> 6;
  if (s >= steps[b]) return;
  int chunk = blockIdx.x & 63;
  int wave = threadIdx.x >> 6;
  int lane = threadIdx.x & 63;
  #pragma unroll
  for (int mi = 0; mi < 2; mi++){
    int m = chunk*8 + wave*2 + mi;
    int start = offsets[b*(kN+1)+m], end = offsets[b*(kN+1)+m+1];
    float4 aC = {0.f,0.f,0.f,0.f}, aH = {0.f,0.f,0.f,0.f};
    float aP = 0.f;
    for (int e=start; e<end; ++e){
      int ent = entries[b*2*kN + e];
      int src = ent & 0xFFFF;
      float pv = (ent & (1<<16)) ? pf[b*kN+src] : pt[b*kN+src];
      aP += pv;
      float4 cv = *(const float4*)&c2[(size_t)(b*kN+src)*kH + lane*4];
      float4 hv = *(const float4*)&h2[(size_t)(b*kN+src)*kH + lane*4];
      aC.x += pv*cv.x; aC.y += pv*cv.y; aC.z += pv*cv.z; aC.w += pv*cv.w;
      aH.x += pv*hv.x; aH.y += pv*hv.y; aH.z += pv*hv.z; aH.w += pv*hv.w;
    }
    float inv = 1.f/(aP + 1e-7f);
    float oc[4] = {aC.x*inv, aC.y*inv, aC.z*inv, aC.w*inv};
    float oh[4] = {aH.x*inv, aH.y*inv, aH.z*inv, aH.w*inv};
    size_t base = (size_t)(b*kN+m)*kH + lane*4;
    *(float4*)&c[base] = *(float4*)oc;
    ushort4 hh4, hl4;
    unsigned short* hhp = (unsigned short*)&hh4;
    unsigned short* hlp = (unsigned short*)&hl4;
    #pragma unroll
    for (int q=0;q<4;q++){
      unsigned short hi = f2bf(oh[q]);
      hhp[q] = hi;
      hlp[q] = f2bf(oh[q] - bf2f(hi));
    }
    *(ushort4*)&h_hi[base] = hh4;
    *(ushort4*)&h_lo[base] = hl4;
    if (lane==0) ip[b*kN+m] = aP;
  }
}

// ---------------- final: logits = concat(c[exit], h[exit]) @ Wo + bo  (split-K) ----------------
// part: grid 500 = 4 k-quarters x 125 v-tiles; partial[(kq*16+b)*kV + v]
__global__ __launch_bounds__(256) void k_out_part(
    const float* __restrict__ c,
    const unsigned short* __restrict__ h_hi, const unsigned short* __restrict__ h_lo,
    const float* __restrict__ Wo,
    const int* __restrict__ exit_idx, float* __restrict__ partial)
{
  int kq = blockIdx.x / 125;
  int vt = blockIdx.x % 125;
  int t = threadIdx.x;
  __shared__ float sf[kB][128];
  for (int i = t; i < kB*128; i += 256){
    int b = i >> 7; int kl = i & 127;
    int f = kq*128 + kl;
    int e = exit_idx[b];
    size_t base = (size_t)(b*kN+e)*kH;
    sf[b][kl] = (f < kH) ? c[base + f]
                         : bf2f(h_hi[base + (f-kH)]) + bf2f(h_lo[base + (f-kH)]);
  }
  __syncthreads();
  int v = vt*256 + t;
  float acc[kB];
  #pragma unroll
  for (int b=0;b<kB;b++) acc[b] = 0.f;
  int k0 = kq*128;
  for (int kl=0; kl<128; kl+=4){
    float w0 = Wo[(size_t)(k0+kl+0)*kV + v];
    float w1 = Wo[(size_t)(k0+kl+1)*kV + v];
    float w2 = Wo[(size_t)(k0+kl+2)*kV + v];
    float w3 = Wo[(size_t)(k0+kl+3)*kV + v];
    #pragma unroll
    for (int b=0;b<kB;b++){
      float4 s4 = *(const float4*)&sf[b][kl];
      acc[b] += s4.x*w0 + s4.y*w1 + s4.z*w2 + s4.w*w3;
    }
  }
  #pragma unroll
  for (int b=0;b<kB;b++) partial[(size_t)(kq*kB+b)*kV + v] = acc[b];
}

__global__ __launch_bounds__(256) void k_out_sum(
    const float* __restrict__ partial, const float* __restrict__ bo,
    float* __restrict__ out)
{
  int v = blockIdx.x*256 + threadIdx.x;
  if (v >= kV) return;
  float bv = bo[v];
  #pragma unroll
  for (int b=0;b<kB;b++){
    float s = bv;
    #pragma unroll
    for (int q=0;q<4;q++) s += partial[(size_t)(q*kB+b)*kV + v];
    out[(size_t)b*kV + v] = s;
  }
}

extern "C" void kernel_launch(void* const* d_in, const int* in_sizes, int n_in,
                              void* d_out, int out_size, void* d_ws, size_t ws_size,
                              hipStream_t stream) {
  const float* emb   = (const float*)d_in[0];
  const float* Wx    = (const float*)d_in[1];
  const float* Wh    = (const float*)d_in[2];
  const float* bias  = (const float*)d_in[3];
  const float* Wb    = (const float*)d_in[4];
  const float* bbias = (const float*)d_in[5];
  const float* Wo    = (const float*)d_in[6];
  const float* bo    = (const float*)d_in[7];
  const int* t_idx   = (const int*)d_in[8];
  const int* f_idx   = (const int*)d_in[9];
  const int* exit_i  = (const int*)d_in[10];
  const int* steps   = (const int*)d_in[11];
  float* out = (float*)d_out;

  char* ws = (char*)d_ws;
  float* X  = (float*)ws; ws += (size_t)kB*kN*kH4*4;
  float* c  = (float*)ws; ws += (size_t)kB*kN*kH*4;
  float* c2 = (float*)ws; ws += (size_t)kB*kN*kH*4;
  float* h2 = (float*)ws; ws += (size_t)kB*kN*kH*4;
  unsigned short* h_hi = (unsigned short*)ws; ws += (size_t)kB*kN*kH*2;
  unsigned short* h_lo = (unsigned short*)ws; ws += (size_t)kB*kN*kH*2;
  unsigned short* Wp_hi = (unsigned short*)ws; ws += (size_t)kH*kH4*2;
  unsigned short* Wp_lo = (unsigned short*)ws; ws += (size_t)kH*kH4*2;
  float* ip = (float*)ws; ws += (size_t)kB*kN*4;
  float* pt = (float*)ws; ws += (size_t)kB*kN*4;
  float* pf = (float*)ws; ws += (size_t)kB*kN*4;
  int* offsets = (int*)ws; ws += ((size_t)kB*(kN+1)*4 + 255) & ~(size_t)255;
  int* entries = (int*)ws; ws += (size_t)kB*2*kN*4;
  float* partial = c2;  // reused after the step loop (8.39MB >= 8.19MB needed)

  k_init<<<256, 256, 0, stream>>>(c, ip, h_hi, h_lo);
  k_csr<<<kB, kN, 0, stream>>>(t_idx, f_idx, offsets, entries);
  k_pack<<<512, 64, 0, stream>>>(Wh, Wp_hi, Wp_lo);
  k_x<<<512, 256, 0, stream>>>(emb, Wx, bias, X);
  for (int s = 0; s < kS; ++s){
    k_step1<<<256, 1024, 0, stream>>>(X, Wp_hi, Wp_lo, h_hi, h_lo, Wb, bbias,
                                      exit_i, steps, c, ip, c2, h2, pt, pf, s);
    k_step2<<<1024, 256, 0, stream>>>(c2, h2, pt, pf, offsets, entries, steps,
                                      c, h_hi, h_lo, ip, s);
  }
  k_out_part<<<500, 256, 0, stream>>>(c, h_hi, h_lo, Wo, exit_i, partial);
  k_out_sum<<<125, 256, 0, stream>>>(partial, bo, out);
}

// Round 4
// 1377.801 us; speedup vs baseline: 3.7344x; 1.5474x over previous
//
#include <hip/hip_runtime.h>
#include <hip/hip_bf16.h>

constexpr int kB  = 16;     // batch
constexpr int kN  = 512;    // nodes
constexpr int kH  = 256;    // hidden
constexpr int kH4 = 1024;   // 4*H
constexpr int kV  = 32000;  // vocab
constexpr int kS  = 48;     // MAX_STEPS (steps[b] <= 47)

typedef __attribute__((ext_vector_type(8))) short short8v;  // 8 bf16 = 4 VGPR
typedef __attribute__((ext_vector_type(4))) float f32x4;
typedef unsigned short u16;

__device__ __forceinline__ float sigm(float x){ return 1.f/(1.f+expf(-x)); }

__device__ __forceinline__ u16 f2bf(float f){
  __hip_bfloat16 h = __float2bfloat16(f);
  return __builtin_bit_cast(u16, h);
}
__device__ __forceinline__ float bf2f(u16 u){
  __hip_bfloat16 h = __builtin_bit_cast(__hip_bfloat16, u);
  return __bfloat162float(h);
}

// ---------------- CSR build (deterministic): one block per example, 512 threads ----------------
__global__ void k_csr(const int* t_idx, const int* f_idx, int* offsets, int* entries){
  int b = blockIdx.x; int t = threadIdx.x; // t = target node m
  __shared__ int tl[kN], fl[kN], sc[kN];
  tl[t] = t_idx[b*kN+t]; fl[t] = f_idx[b*kN+t];
  __syncthreads();
  int cnt = 0;
  for (int n=0;n<kN;n++) cnt += (tl[n]==t) + (fl[n]==t);
  sc[t] = cnt; __syncthreads();
  for (int off=1; off<kN; off<<=1){
    int v = sc[t];
    int add = (t>=off)? sc[t-off] : 0;
    __syncthreads();
    sc[t] = v + add;
    __syncthreads();
  }
  int excl = sc[t] - cnt;
  offsets[b*(kN+1)+t] = excl;
  if (t==0) offsets[b*(kN+1)+kN] = 2*kN;
  int pos = b*2*kN + excl;
  for (int n=0;n<kN;n++) if (tl[n]==t) entries[pos++] = n;            // true first
  for (int n=0;n<kN;n++) if (fl[n]==t) entries[pos++] = n | (1<<16);  // then false
}

// ---------------- split fp32 -> bf16 hi/lo (emb) ----------------
__global__ void k_split(const float* __restrict__ in, u16* __restrict__ hi, u16* __restrict__ lo){
  int idx = blockIdx.x*blockDim.x + threadIdx.x;  // 524288 threads x 4 elems
  float4 v = ((const float4*)in)[idx];
  float a[4] = {v.x, v.y, v.z, v.w};
  ushort4 h4, l4;
  u16* hp = (u16*)&h4; u16* lp = (u16*)&l4;
  #pragma unroll
  for (int q=0;q<4;q++){
    u16 h = f2bf(a[q]);
    hp[q] = h;
    lp[q] = f2bf(a[q] - bf2f(h));
  }
  ((ushort4*)hi)[idx] = h4;
  ((ushort4*)lo)[idx] = l4;
}

// ---------------- pack a [256,1024] weight into MFMA B-fragment order, split hi/lo ----------------
// frag fi = ((kt*4 + wo)*16 + (g*4+j)); lane l supplies B[k][col] for
// k = kt*32 + (l>>4)*8 + jj, col = g*256 + wo*64 + j*16 + (l&15)
__global__ void k_pack(const float* __restrict__ W, u16* __restrict__ ph, u16* __restrict__ pl){
  int fi = blockIdx.x; int l = threadIdx.x; // 64 threads
  int kt = fi >> 6; int wo = (fi>>4)&3; int cfl = fi & 15;
  int g = cfl>>2; int j = cfl&3;
  int col = g*kH + wo*64 + j*16 + (l&15);
  int kb = kt*32 + (l>>4)*8;
  size_t o = (size_t)fi*512 + (size_t)l*8;
  #pragma unroll
  for (int jj=0; jj<8; ++jj){
    float w = W[(size_t)(kb+jj)*kH4 + col];
    u16 hi = f2bf(w);
    u16 lo = f2bf(w - bf2f(hi));
    ph[o+jj] = hi; pl[o+jj] = lo;
  }
}

// ---------------- X = emb @ Wx + bias (MFMA), written in fragment order ----------------
// grid 256 blocks (16 ex x 16 rowblocks of 32), 1024 threads = 16 waves.
__global__ __launch_bounds__(1024) void k_x_mfma(
    const u16* __restrict__ e_hi, const u16* __restrict__ e_lo,
    const u16* __restrict__ Wxp_hi, const u16* __restrict__ Wxp_lo,
    const float* __restrict__ bias, float* __restrict__ Xp)
{
  int blk = blockIdx.x;
  int b = blk >> 4; int row0 = (blk & 15) * 32;
  int tid = threadIdx.x;
  int wn = tid >> 6, lane = tid & 63;
  int lrow = lane & 15, lk = lane >> 4;
  int ch = wn*16 + lrow;

  f32x4 acc[2][4];
  #pragma unroll
  for (int r=0;r<2;r++)
    #pragma unroll
    for (int g=0;g<4;g++){
      float bv = bias[g*kH + ch];
      acc[r][g] = (f32x4){bv,bv,bv,bv};
    }

  const u16* eh = e_hi + ((size_t)b*kN + row0)*kH;
  const u16* el = e_lo + ((size_t)b*kN + row0)*kH;
  int wo = wn >> 2, jj4 = wn & 3;
  for (int kt=0; kt<8; ++kt){
    short8v a_hi[2], a_lo[2];
    #pragma unroll
    for (int r=0;r<2;r++){
      size_t off = (size_t)(r*16+lrow)*kH + kt*32 + lk*8;
      a_hi[r] = *(const short8v*)(eh + off);
      a_lo[r] = *(const short8v*)(el + off);
    }
    #pragma unroll
    for (int g=0; g<4; ++g){
      size_t fb = ((size_t)((kt*4+wo)*16 + g*4 + jj4))*512 + (size_t)lane*8;
      short8v bh = *(const short8v*)(Wxp_hi+fb);
      short8v bl = *(const short8v*)(Wxp_lo+fb);
      #pragma unroll
      for (int r=0;r<2;r++){
        acc[r][g] = __builtin_amdgcn_mfma_f32_16x16x32_bf16(a_hi[r], bh, acc[r][g], 0,0,0);
        acc[r][g] = __builtin_amdgcn_mfma_f32_16x16x32_bf16(a_lo[r], bh, acc[r][g], 0,0,0);
        acc[r][g] = __builtin_amdgcn_mfma_f32_16x16x32_bf16(a_hi[r], bl, acc[r][g], 0,0,0);
      }
    }
  }

  f32x4* xb = (f32x4*)(Xp + ((size_t)blk*16 + wn)*2048);
  #pragma unroll
  for (int r=0;r<2;r++)
    #pragma unroll
    for (int g=0;g<4;g++)
      xb[(r*4+g)*64 + lane] = acc[r][g];
}

// ---------------- fused step: gather(step s-1) + LSTM/branch(step s) ----------------
// grid 256 blocks (16 ex x 16 rowblocks of 32), 1024 threads = 16 waves.
__global__ __launch_bounds__(1024) void k_fused(
    const float* __restrict__ Xp,
    const u16* __restrict__ Wp_hi, const u16* __restrict__ Wp_lo,
    const float* __restrict__ Wb, const float* __restrict__ bb,
    const int* __restrict__ exit_idx, const int* __restrict__ steps,
    const int* __restrict__ offsets, const int* __restrict__ entries,
    const float* __restrict__ c2r, const float* __restrict__ h2r,
    const float* __restrict__ ptr_, const float* __restrict__ pfr,
    float* __restrict__ c2w, float* __restrict__ h2w,
    float* __restrict__ ptw, float* __restrict__ pfw,
    float* __restrict__ exf, int s)
{
  int blk = blockIdx.x;
  int b = blk >> 4;
  int st = steps[b];
  if (s > st) return;
  int row0 = (blk & 15) * 32;
  int tid = threadIdx.x;
  int wn = tid >> 6, lane = tid & 63;
  int lrow = lane & 15, lk = lane >> 4;
  int ch = wn*16 + lrow;
  int eb = exit_idx[b];
  bool fin = (s == st);

  __shared__ u16 hh_lds[32*256];   // bf16-hi of gathered h, XOR-swizzled rows
  __shared__ u16 hl_lds[32*256];   // bf16-lo
  __shared__ float c_lds[32][260]; // gathered c (padded stride)
  __shared__ float ip_lds[32];
  __shared__ float prs[16][32][2];

  // issue X loads early (independent of gather)
  f32x4 acc[2][4];
  {
    const f32x4* xb = (const f32x4*)(Xp + ((size_t)blk*16 + wn)*2048);
    #pragma unroll
    for (int r=0;r<2;r++)
      #pragma unroll
      for (int g=0;g<4;g++)
        acc[r][g] = xb[(r*4+g)*64 + lane];
  }

  // ---- Phase A: gather previous step's outputs into LDS (or init at s==0) ----
  if (s == 0){
    for (int i = tid; i < 32*256; i += 1024){ hh_lds[i] = 0; hl_lds[i] = 0; }
    for (int i = tid; i < 32*260; i += 1024) (&c_lds[0][0])[i] = 0.f;
    if (tid < 32) ip_lds[tid] = (row0 + tid == 0) ? 1.f : 0.f;
  } else {
    const float* c2rb = c2r + (size_t)b*kN*kH;
    const float* h2rb = h2r + (size_t)b*kN*kH;
    #pragma unroll
    for (int mi = 0; mi < 2; ++mi){
      int mloc = wn*2 + mi;
      int m = row0 + mloc;
      int start = offsets[b*(kN+1)+m], end = offsets[b*(kN+1)+m+1];
      float4 aC = {0.f,0.f,0.f,0.f}, aH = {0.f,0.f,0.f,0.f};
      float aP = 0.f;
      for (int e = start; e < end; ++e){
        int ent = entries[b*2*kN + e];
        int src = ent & 0xFFFF;
        float pv = (ent >> 16) ? pfr[b*kN+src] : ptr_[b*kN+src];
        aP += pv;
        float4 cv = *(const float4*)&c2rb[(size_t)src*kH + lane*4];
        float4 hv = *(const float4*)&h2rb[(size_t)src*kH + lane*4];
        aC.x += pv*cv.x; aC.y += pv*cv.y; aC.z += pv*cv.z; aC.w += pv*cv.w;
        aH.x += pv*hv.x; aH.y += pv*hv.y; aH.z += pv*hv.z; aH.w += pv*hv.w;
      }
      float inv = 1.f/(aP + 1e-7f);
      float oc[4] = {aC.x*inv, aC.y*inv, aC.z*inv, aC.w*inv};
      float oh[4] = {aH.x*inv, aH.y*inv, aH.z*inv, aH.w*inv};
      if (fin){
        if (m == eb){
          *(float4*)&exf[b*2*kH + lane*4]      = *(float4*)oc;
          *(float4*)&exf[b*2*kH + kH + lane*4] = *(float4*)oh;
        }
      } else {
        *(float4*)&c_lds[mloc][lane*4] = *(float4*)oc;
        ushort4 hh4, hl4;
        u16* hhp = (u16*)&hh4; u16* hlp = (u16*)&hl4;
        #pragma unroll
        for (int q=0;q<4;q++){
          u16 hi = f2bf(oh[q]);
          hhp[q] = hi;
          hlp[q] = f2bf(oh[q] - bf2f(hi));
        }
        int bo2 = (mloc*512 + lane*8) ^ ((mloc&7)<<4);
        *(ushort4*)((char*)hh_lds + bo2) = hh4;
        *(ushort4*)((char*)hl_lds + bo2) = hl4;
        if (lane == 0) ip_lds[mloc] = aP;
      }
    }
  }
  if (fin) return;
  __syncthreads();

  // ---- Phase B: MFMA K-loop (3-term split-bf16), A from swizzled LDS ----
  int wo = wn >> 2, jj4 = wn & 3;
  for (int kt=0; kt<8; ++kt){
    short8v a_hi[2], a_lo[2];
    #pragma unroll
    for (int r=0;r<2;r++){
      int row = r*16 + lrow;
      int bo2 = (row*512 + kt*64 + lk*16) ^ ((row&7)<<4);
      a_hi[r] = *(const short8v*)((char*)hh_lds + bo2);
      a_lo[r] = *(const short8v*)((char*)hl_lds + bo2);
    }
    #pragma unroll
    for (int g=0; g<4; ++g){
      size_t fb = ((size_t)((kt*4+wo)*16 + g*4 + jj4))*512 + (size_t)lane*8;
      short8v bh = *(const short8v*)(Wp_hi+fb);
      short8v bl = *(const short8v*)(Wp_lo+fb);
      #pragma unroll
      for (int r=0;r<2;r++){
        acc[r][g] = __builtin_amdgcn_mfma_f32_16x16x32_bf16(a_hi[r], bh, acc[r][g], 0,0,0);
        acc[r][g] = __builtin_amdgcn_mfma_f32_16x16x32_bf16(a_lo[r], bh, acc[r][g], 0,0,0);
        acc[r][g] = __builtin_amdgcn_mfma_f32_16x16x32_bf16(a_hi[r], bl, acc[r][g], 0,0,0);
      }
    }
  }

  // ---- epilogue: gates, exit override, branch-logit partials ----
  float wbc0 = Wb[ch*2+0],      wbc1 = Wb[ch*2+1];
  float wbh0 = Wb[(kH+ch)*2+0], wbh1 = Wb[(kH+ch)*2+1];
  float pr0[8], pr1[8];

  #pragma unroll
  for (int r=0;r<2;r++)
    #pragma unroll
    for (int reg=0;reg<4;reg++){
      int rloc = r*16 + lk*4 + reg;
      int row = row0 + rloc;
      float zi = acc[r][0][reg];
      float zf = acc[r][1][reg];
      float zg = acc[r][2][reg];
      float zo = acc[r][3][reg];
      float cp = c_lds[rloc][ch];
      float c2v = sigm(zf)*cp + sigm(zi)*tanhf(zg);
      float h2v = sigm(zo)*tanhf(c2v);
      if (row == eb){
        int bo2 = (rloc*512 + ch*2) ^ ((rloc&7)<<4);
        c2v = cp;
        h2v = bf2f(*(const u16*)((const char*)hh_lds + bo2))
            + bf2f(*(const u16*)((const char*)hl_lds + bo2));
      }
      size_t gb = ((size_t)b*kN + row)*kH + ch;
      c2w[gb] = c2v; h2w[gb] = h2v;
      int pi = r*4+reg;
      pr0[pi] = c2v*wbc0 + h2v*wbh0;
      pr1[pi] = c2v*wbc1 + h2v*wbh1;
    }

  #pragma unroll
  for (int off=1; off<16; off<<=1){
    #pragma unroll
    for (int i=0;i<8;i++){
      pr0[i] += __shfl_xor(pr0[i], off);
      pr1[i] += __shfl_xor(pr1[i], off);
    }
  }
  if (lrow == 0){
    #pragma unroll
    for (int r=0;r<2;r++)
      #pragma unroll
      for (int reg=0;reg<4;reg++){
        int lr = r*16 + lk*4 + reg;
        prs[wn][lr][0] = pr0[r*4+reg];
        prs[wn][lr][1] = pr1[r*4+reg];
      }
  }
  __syncthreads();
  if (tid < 32){
    int row = row0 + tid;
    float u0 = bb[0], u1 = bb[1];
    #pragma unroll
    for (int w=0;w<16;w++){ u0 += prs[w][tid][0]; u1 += prs[w][tid][1]; }
    float mx = fmaxf(u0,u1);
    float e0 = expf(u0-mx), e1 = expf(u1-mx);
    float inv = 1.f/(e0+e1);
    float ipv = ip_lds[tid];
    ptw[b*kN+row] = (e0*inv)*ipv;
    pfw[b*kN+row] = (e1*inv)*ipv;
  }
}

// ---------------- final: logits = exitstate @ Wo + bo  (split-K) ----------------
__global__ __launch_bounds__(256) void k_out_part(
    const float* __restrict__ exf, const float* __restrict__ Wo,
    float* __restrict__ partial)
{
  int kq = blockIdx.x / 125;
  int vt = blockIdx.x % 125;
  int t = threadIdx.x;
  __shared__ float sf[kB][128];
  for (int i = t; i < kB*128; i += 256){
    int b = i >> 7; int kl = i & 127;
    sf[b][kl] = exf[b*2*kH + kq*128 + kl];
  }
  __syncthreads();
  int v = vt*256 + t;
  float acc[kB];
  #pragma unroll
  for (int b=0;b<kB;b++) acc[b] = 0.f;
  int k0 = kq*128;
  for (int kl=0; kl<128; kl+=4){
    float w0 = Wo[(size_t)(k0+kl+0)*kV + v];
    float w1 = Wo[(size_t)(k0+kl+1)*kV + v];
    float w2 = Wo[(size_t)(k0+kl+2)*kV + v];
    float w3 = Wo[(size_t)(k0+kl+3)*kV + v];
    #pragma unroll
    for (int b=0;b<kB;b++){
      float4 s4 = *(const float4*)&sf[b][kl];
      acc[b] += s4.x*w0 + s4.y*w1 + s4.z*w2 + s4.w*w3;
    }
  }
  #pragma unroll
  for (int b=0;b<kB;b++) partial[(size_t)(kq*kB+b)*kV + v] = acc[b];
}

__global__ __launch_bounds__(256) void k_out_sum(
    const float* __restrict__ partial, const float* __restrict__ bo,
    float* __restrict__ out)
{
  int v = blockIdx.x*256 + threadIdx.x;
  if (v >= kV) return;
  float bv = bo[v];
  #pragma unroll
  for (int b=0;b<kB;b++){
    float s = bv;
    #pragma unroll
    for (int q=0;q<4;q++) s += partial[(size_t)(q*kB+b)*kV + v];
    out[(size_t)b*kV + v] = s;
  }
}

extern "C" void kernel_launch(void* const* d_in, const int* in_sizes, int n_in,
                              void* d_out, int out_size, void* d_ws, size_t ws_size,
                              hipStream_t stream) {
  const float* emb   = (const float*)d_in[0];
  const float* Wx    = (const float*)d_in[1];
  const float* Wh    = (const float*)d_in[2];
  const float* bias  = (const float*)d_in[3];
  const float* Wb    = (const float*)d_in[4];
  const float* bbias = (const float*)d_in[5];
  const float* Wo    = (const float*)d_in[6];
  const float* bo    = (const float*)d_in[7];
  const int* t_idx   = (const int*)d_in[8];
  const int* f_idx   = (const int*)d_in[9];
  const int* exit_i  = (const int*)d_in[10];
  const int* steps   = (const int*)d_in[11];
  float* out = (float*)d_out;

  char* ws = (char*)d_ws;
  float* Xp  = (float*)ws; ws += (size_t)kB*kN*kH4*4;     // 33.55 MB, fragment-ordered X
  float* c2a = (float*)ws; ws += (size_t)kB*kN*kH*4;      // ping set (written at even s)
  float* h2a = (float*)ws; ws += (size_t)kB*kN*kH*4;
  char* setB = ws;
  float* c2b = (float*)ws; ws += (size_t)kB*kN*kH*4;      // pong set (written at odd s)
  float* h2b = (float*)ws; ws += (size_t)kB*kN*kH*4;
  u16* Wp_hi = (u16*)ws;  ws += (size_t)kH*kH4*2;
  u16* Wp_lo = (u16*)ws;  ws += (size_t)kH*kH4*2;
  float* pta = (float*)ws; ws += (size_t)kB*kN*4;
  float* pfa = (float*)ws; ws += (size_t)kB*kN*4;
  float* ptb = (float*)ws; ws += (size_t)kB*kN*4;
  float* pfb = (float*)ws; ws += (size_t)kB*kN*4;
  float* exf = (float*)ws; ws += (size_t)kB*2*kH*4;
  int* offsets = (int*)ws; ws += ((size_t)kB*(kN+1)*4 + 255) & ~(size_t)255;
  int* entries = (int*)ws; ws += (size_t)kB*2*kN*4;
  // aliases: emb-split + packed Wx live only until k_x_mfma completes,
  // before any write to the pong set (first written at s=1).
  u16* emb_hi = (u16*)setB;                                   // 4 MB
  u16* emb_lo = (u16*)(setB + (size_t)kB*kN*kH*2);            // 4 MB
  u16* Wxp_hi = (u16*)(setB + (size_t)kB*kN*kH*4);            // 512 KB
  u16* Wxp_lo = (u16*)(setB + (size_t)kB*kN*kH*4 + (size_t)kH*kH4*2);
  float* partial = Xp;  // reused after the step loop

  k_csr<<<kB, kN, 0, stream>>>(t_idx, f_idx, offsets, entries);
  k_split<<<2048, 256, 0, stream>>>(emb, emb_hi, emb_lo);
  k_pack<<<512, 64, 0, stream>>>(Wh, Wp_hi, Wp_lo);
  k_pack<<<512, 64, 0, stream>>>(Wx, Wxp_hi, Wxp_lo);
  k_x_mfma<<<256, 1024, 0, stream>>>(emb_hi, emb_lo, Wxp_hi, Wxp_lo, bias, Xp);

  for (int s = 0; s < kS; ++s){
    bool even = ((s & 1) == 0);
    k_fused<<<256, 1024, 0, stream>>>(
        Xp, Wp_hi, Wp_lo, Wb, bbias, exit_i, steps, offsets, entries,
        even ? c2b : c2a, even ? h2b : h2a, even ? ptb : pta, even ? pfb : pfa,  // read (s-1)
        even ? c2a : c2b, even ? h2a : h2b, even ? pta : ptb, even ? pfa : pfb,  // write (s)
        exf, s);
  }

  k_out_part<<<500, 256, 0, stream>>>(exf, Wo, partial);
  k_out_sum<<<125, 256, 0, stream>>>(partial, bo, out);
}

// Round 5
// 1154.520 us; speedup vs baseline: 4.4566x; 1.1934x over previous
//
#include <hip/hip_runtime.h>
#include <hip/hip_bf16.h>

constexpr int kB  = 16;     // batch
constexpr int kN  = 512;    // nodes
constexpr int kH  = 256;    // hidden
constexpr int kH4 = 1024;   // 4*H
constexpr int kV  = 32000;  // vocab
constexpr int kS  = 48;     // MAX_STEPS (steps[b] <= 47)

typedef __attribute__((ext_vector_type(8))) short short8v;  // 8 bf16 = 4 VGPR
typedef __attribute__((ext_vector_type(4))) float f32x4;
typedef unsigned short u16;

__device__ __forceinline__ float sigm(float x){ return 1.f/(1.f+expf(-x)); }

__device__ __forceinline__ u16 f2bf(float f){
  __hip_bfloat16 h = __float2bfloat16(f);
  return __builtin_bit_cast(u16, h);
}
__device__ __forceinline__ float bf2f(u16 u){
  __hip_bfloat16 h = __builtin_bit_cast(__hip_bfloat16, u);
  return __bfloat162float(h);
}

// ---------------- CSR build (deterministic): atomics for counts/placement + bucket sort ----------------
// Counts via atomicAdd are order-independent; bucket entries are then sorted ascending,
// which (encoding (branch<<16)|n) reproduces the reference order: true by n, then false by n.
__global__ void k_csr(const int* t_idx, const int* f_idx, int* offsets, int* entries){
  int b = blockIdx.x; int t = threadIdx.x; // 512 threads; t = source node AND target node
  __shared__ int tl[kN], fl[kN], cnt[kN], pos[kN], ebuf[2*kN];
  tl[t] = t_idx[b*kN+t]; fl[t] = f_idx[b*kN+t];
  cnt[t] = 0;
  __syncthreads();
  atomicAdd(&cnt[tl[t]], 1);
  atomicAdd(&cnt[fl[t]], 1);
  __syncthreads();
  int myc = cnt[t];
  pos[t] = myc;
  __syncthreads();
  for (int off=1; off<kN; off<<=1){   // Hillis-Steele inclusive scan
    int v = pos[t];
    int add = (t>=off)? pos[t-off] : 0;
    __syncthreads();
    pos[t] = v + add;
    __syncthreads();
  }
  int excl = pos[t] - myc;
  offsets[b*(kN+1)+t] = excl;
  if (t==0) offsets[b*(kN+1)+kN] = 2*kN;
  __syncthreads();
  pos[t] = excl;   // placement cursor
  __syncthreads();
  int p1 = atomicAdd(&pos[tl[t]], 1); ebuf[p1] = t;            // true branch
  int p2 = atomicAdd(&pos[fl[t]], 1); ebuf[p2] = t | (1<<16);  // false branch
  __syncthreads();
  // sort own bucket ascending (disjoint ranges per thread)
  for (int i = excl+1; i < excl+myc; ++i){
    int v = ebuf[i]; int j = i-1;
    while (j >= excl && ebuf[j] > v){ ebuf[j+1] = ebuf[j]; --j; }
    ebuf[j+1] = v;
  }
  __syncthreads();
  entries[b*2*kN + t]      = ebuf[t];
  entries[b*2*kN + kN + t] = ebuf[kN + t];
}

// ---------------- split fp32 -> bf16 hi/lo (emb) ----------------
__global__ void k_split(const float* __restrict__ in, u16* __restrict__ hi, u16* __restrict__ lo){
  int idx = blockIdx.x*blockDim.x + threadIdx.x;  // 524288 threads x 4 elems
  float4 v = ((const float4*)in)[idx];
  float a[4] = {v.x, v.y, v.z, v.w};
  ushort4 h4, l4;
  u16* hp = (u16*)&h4; u16* lp = (u16*)&l4;
  #pragma unroll
  for (int q=0;q<4;q++){
    u16 h = f2bf(a[q]);
    hp[q] = h;
    lp[q] = f2bf(a[q] - bf2f(h));
  }
  ((ushort4*)hi)[idx] = h4;
  ((ushort4*)lo)[idx] = l4;
}

// ---------------- pack a [256,1024] weight into MFMA B-fragment order, split hi/lo ----------------
// frag fi = ((kt*4 + wo)*16 + (g*4+j)); lane l supplies B[k][col] for
// k = kt*32 + (l>>4)*8 + jj, col = g*256 + wo*64 + j*16 + (l&15)
__global__ void k_pack(const float* __restrict__ W, u16* __restrict__ ph, u16* __restrict__ pl){
  int fi = blockIdx.x; int l = threadIdx.x; // 64 threads
  int kt = fi >> 6; int wo = (fi>>4)&3; int cfl = fi & 15;
  int g = cfl>>2; int j = cfl&3;
  int col = g*kH + wo*64 + j*16 + (l&15);
  int kb = kt*32 + (l>>4)*8;
  size_t o = (size_t)fi*512 + (size_t)l*8;
  #pragma unroll
  for (int jj=0; jj<8; ++jj){
    float w = W[(size_t)(kb+jj)*kH4 + col];
    u16 hi = f2bf(w);
    u16 lo = f2bf(w - bf2f(hi));
    ph[o+jj] = hi; pl[o+jj] = lo;
  }
}

// ---------------- X = emb @ Wx + bias (MFMA, 3-term), written in fragment order ----------------
__global__ __launch_bounds__(1024) void k_x_mfma(
    const u16* __restrict__ e_hi, const u16* __restrict__ e_lo,
    const u16* __restrict__ Wxp_hi, const u16* __restrict__ Wxp_lo,
    const float* __restrict__ bias, float* __restrict__ Xp)
{
  int blk = blockIdx.x;
  int b = blk >> 4; int row0 = (blk & 15) * 32;
  int tid = threadIdx.x;
  int wn = tid >> 6, lane = tid & 63;
  int lrow = lane & 15, lk = lane >> 4;
  int ch = wn*16 + lrow;

  f32x4 acc[2][4];
  #pragma unroll
  for (int r=0;r<2;r++)
    #pragma unroll
    for (int g=0;g<4;g++){
      float bv = bias[g*kH + ch];
      acc[r][g] = (f32x4){bv,bv,bv,bv};
    }

  const u16* eh = e_hi + ((size_t)b*kN + row0)*kH;
  const u16* el = e_lo + ((size_t)b*kN + row0)*kH;
  int wo = wn >> 2, jj4 = wn & 3;
  for (int kt=0; kt<8; ++kt){
    short8v a_hi[2], a_lo[2];
    #pragma unroll
    for (int r=0;r<2;r++){
      size_t off = (size_t)(r*16+lrow)*kH + kt*32 + lk*8;
      a_hi[r] = *(const short8v*)(eh + off);
      a_lo[r] = *(const short8v*)(el + off);
    }
    #pragma unroll
    for (int g=0; g<4; ++g){
      size_t fb = ((size_t)((kt*4+wo)*16 + g*4 + jj4))*512 + (size_t)lane*8;
      short8v bh = *(const short8v*)(Wxp_hi+fb);
      short8v bl = *(const short8v*)(Wxp_lo+fb);
      #pragma unroll
      for (int r=0;r<2;r++){
        acc[r][g] = __builtin_amdgcn_mfma_f32_16x16x32_bf16(a_hi[r], bh, acc[r][g], 0,0,0);
        acc[r][g] = __builtin_amdgcn_mfma_f32_16x16x32_bf16(a_lo[r], bh, acc[r][g], 0,0,0);
        acc[r][g] = __builtin_amdgcn_mfma_f32_16x16x32_bf16(a_hi[r], bl, acc[r][g], 0,0,0);
      }
    }
  }

  f32x4* xb = (f32x4*)(Xp + ((size_t)blk*16 + wn)*2048);
  #pragma unroll
  for (int r=0;r<2;r++)
    #pragma unroll
    for (int g=0;g<4;g++)
      xb[(r*4+g)*64 + lane] = acc[r][g];
}

// ---------------- fused step: gather(step s-1) + LSTM/branch(step s), 2-term MFMA ----------------
// grid 256 blocks (16 ex x 16 rowblocks of 32), 1024 threads = 16 waves.
__global__ __launch_bounds__(1024) void k_fused(
    const float* __restrict__ Xp,
    const u16* __restrict__ Wp_hi,
    const float* __restrict__ Wb, const float* __restrict__ bb,
    const int* __restrict__ exit_idx, const int* __restrict__ steps,
    const int* __restrict__ offsets, const int* __restrict__ entries,
    const float* __restrict__ c2r, const float* __restrict__ h2r,
    const float* __restrict__ ptr_, const float* __restrict__ pfr,
    float* __restrict__ c2w, float* __restrict__ h2w,
    float* __restrict__ ptw, float* __restrict__ pfw,
    float* __restrict__ exf, int s)
{
  int blk = blockIdx.x;
  int b = blk >> 4;
  int st = steps[b];
  if (s > st) return;
  int row0 = (blk & 15) * 32;
  int tid = threadIdx.x;
  int wn = tid >> 6, lane = tid & 63;
  int lrow = lane & 15, lk = lane >> 4;
  int ch = wn*16 + lrow;
  int eb = exit_idx[b];
  bool fin = (s == st);

  __shared__ u16 hh_lds[32*256];   // bf16-hi of gathered h, XOR-swizzled rows
  __shared__ u16 hl_lds[32*256];   // bf16-lo
  __shared__ float c_lds[32][260]; // gathered c (padded stride)
  __shared__ float ip_lds[32];
  __shared__ float prs[16][32][2];

  // issue X loads early (independent of gather)
  f32x4 acc[2][4];
  {
    const f32x4* xb = (const f32x4*)(Xp + ((size_t)blk*16 + wn)*2048);
    #pragma unroll
    for (int r=0;r<2;r++)
      #pragma unroll
      for (int g=0;g<4;g++)
        acc[r][g] = xb[(r*4+g)*64 + lane];
  }

  // ---- Phase A: gather previous step's outputs into LDS (or init at s==0) ----
  if (s == 0){
    for (int i = tid; i < 32*256; i += 1024){ hh_lds[i] = 0; hl_lds[i] = 0; }
    for (int i = tid; i < 32*260; i += 1024) (&c_lds[0][0])[i] = 0.f;
    if (tid < 32) ip_lds[tid] = (row0 + tid == 0) ? 1.f : 0.f;
  } else {
    const float* c2rb = c2r + (size_t)b*kN*kH;
    const float* h2rb = h2r + (size_t)b*kN*kH;
    #pragma unroll
    for (int mi = 0; mi < 2; ++mi){
      int mloc = wn*2 + mi;
      int m = row0 + mloc;
      int start = offsets[b*(kN+1)+m], end = offsets[b*(kN+1)+m+1];
      float4 aC = {0.f,0.f,0.f,0.f}, aH = {0.f,0.f,0.f,0.f};
      float aP = 0.f;
      for (int e = start; e < end; ++e){
        int ent = entries[b*2*kN + e];
        int src = ent & 0xFFFF;
        float pv = (ent >> 16) ? pfr[b*kN+src] : ptr_[b*kN+src];
        aP += pv;
        float4 cv = *(const float4*)&c2rb[(size_t)src*kH + lane*4];
        float4 hv = *(const float4*)&h2rb[(size_t)src*kH + lane*4];
        aC.x += pv*cv.x; aC.y += pv*cv.y; aC.z += pv*cv.z; aC.w += pv*cv.w;
        aH.x += pv*hv.x; aH.y += pv*hv.y; aH.z += pv*hv.z; aH.w += pv*hv.w;
      }
      float inv = 1.f/(aP + 1e-7f);
      float oc[4] = {aC.x*inv, aC.y*inv, aC.z*inv, aC.w*inv};
      float oh[4] = {aH.x*inv, aH.y*inv, aH.z*inv, aH.w*inv};
      if (fin){
        if (m == eb){
          *(float4*)&exf[b*2*kH + lane*4]      = *(float4*)oc;
          *(float4*)&exf[b*2*kH + kH + lane*4] = *(float4*)oh;
        }
      } else {
        *(float4*)&c_lds[mloc][lane*4] = *(float4*)oc;
        ushort4 hh4, hl4;
        u16* hhp = (u16*)&hh4; u16* hlp = (u16*)&hl4;
        #pragma unroll
        for (int q=0;q<4;q++){
          u16 hi = f2bf(oh[q]);
          hhp[q] = hi;
          hlp[q] = f2bf(oh[q] - bf2f(hi));
        }
        int bo2 = (mloc*512 + lane*8) ^ ((mloc&7)<<4);
        *(ushort4*)((char*)hh_lds + bo2) = hh4;
        *(ushort4*)((char*)hl_lds + bo2) = hl4;
        if (lane == 0) ip_lds[mloc] = aP;
      }
    }
  }
  if (fin) return;
  __syncthreads();

  // ---- Phase B: MFMA K-loop (2-term: full-precision h x bf16-hi W), A from swizzled LDS ----
  int wo = wn >> 2, jj4 = wn & 3;
  for (int kt=0; kt<8; ++kt){
    short8v a_hi[2], a_lo[2];
    #pragma unroll
    for (int r=0;r<2;r++){
      int row = r*16 + lrow;
      int bo2 = (row*512 + kt*64 + lk*16) ^ ((row&7)<<4);
      a_hi[r] = *(const short8v*)((char*)hh_lds + bo2);
      a_lo[r] = *(const short8v*)((char*)hl_lds + bo2);
    }
    #pragma unroll
    for (int g=0; g<4; ++g){
      size_t fb = ((size_t)((kt*4+wo)*16 + g*4 + jj4))*512 + (size_t)lane*8;
      short8v bh = *(const short8v*)(Wp_hi+fb);
      #pragma unroll
      for (int r=0;r<2;r++){
        acc[r][g] = __builtin_amdgcn_mfma_f32_16x16x32_bf16(a_hi[r], bh, acc[r][g], 0,0,0);
        acc[r][g] = __builtin_amdgcn_mfma_f32_16x16x32_bf16(a_lo[r], bh, acc[r][g], 0,0,0);
      }
    }
  }

  // ---- epilogue: gates, exit override, branch-logit partials ----
  float wbc0 = Wb[ch*2+0],      wbc1 = Wb[ch*2+1];
  float wbh0 = Wb[(kH+ch)*2+0], wbh1 = Wb[(kH+ch)*2+1];
  float pr0[8], pr1[8];

  #pragma unroll
  for (int r=0;r<2;r++)
    #pragma unroll
    for (int reg=0;reg<4;reg++){
      int rloc = r*16 + lk*4 + reg;
      int row = row0 + rloc;
      float zi = acc[r][0][reg];
      float zf = acc[r][1][reg];
      float zg = acc[r][2][reg];
      float zo = acc[r][3][reg];
      float cp = c_lds[rloc][ch];
      float c2v = sigm(zf)*cp + sigm(zi)*tanhf(zg);
      float h2v = sigm(zo)*tanhf(c2v);
      if (row == eb){
        int bo2 = (rloc*512 + ch*2) ^ ((rloc&7)<<4);
        c2v = cp;
        h2v = bf2f(*(const u16*)((const char*)hh_lds + bo2))
            + bf2f(*(const u16*)((const char*)hl_lds + bo2));
      }
      size_t gb = ((size_t)b*kN + row)*kH + ch;
      c2w[gb] = c2v; h2w[gb] = h2v;
      int pi = r*4+reg;
      pr0[pi] = c2v*wbc0 + h2v*wbh0;
      pr1[pi] = c2v*wbc1 + h2v*wbh1;
    }

  #pragma unroll
  for (int off=1; off<16; off<<=1){
    #pragma unroll
    for (int i=0;i<8;i++){
      pr0[i] += __shfl_xor(pr0[i], off);
      pr1[i] += __shfl_xor(pr1[i], off);
    }
  }
  if (lrow == 0){
    #pragma unroll
    for (int r=0;r<2;r++)
      #pragma unroll
      for (int reg=0;reg<4;reg++){
        int lr = r*16 + lk*4 + reg;
        prs[wn][lr][0] = pr0[r*4+reg];
        prs[wn][lr][1] = pr1[r*4+reg];
      }
  }
  __syncthreads();
  if (tid < 32){
    int row = row0 + tid;
    float u0 = bb[0], u1 = bb[1];
    #pragma unroll
    for (int w=0;w<16;w++){ u0 += prs[w][tid][0]; u1 += prs[w][tid][1]; }
    float mx = fmaxf(u0,u1);
    float e0 = expf(u0-mx), e1 = expf(u1-mx);
    float inv = 1.f/(e0+e1);
    float ipv = ip_lds[tid];
    ptw[b*kN+row] = (e0*inv)*ipv;
    pfw[b*kN+row] = (e1*inv)*ipv;
  }
}

// ---------------- final: logits = exitstate @ Wo + bo  (split-K) ----------------
__global__ __launch_bounds__(256) void k_out_part(
    const float* __restrict__ exf, const float* __restrict__ Wo,
    float* __restrict__ partial)
{
  int kq = blockIdx.x / 125;
  int vt = blockIdx.x % 125;
  int t = threadIdx.x;
  __shared__ float sf[kB][128];
  for (int i = t; i < kB*128; i += 256){
    int b = i >> 7; int kl = i & 127;
    sf[b][kl] = exf[b*2*kH + kq*128 + kl];
  }
  __syncthreads();
  int v = vt*256 + t;
  float acc[kB];
  #pragma unroll
  for (int b=0;b<kB;b++) acc[b] = 0.f;
  int k0 = kq*128;
  for (int kl=0; kl<128; kl+=4){
    float w0 = Wo[(size_t)(k0+kl+0)*kV + v];
    float w1 = Wo[(size_t)(k0+kl+1)*kV + v];
    float w2 = Wo[(size_t)(k0+kl+2)*kV + v];
    float w3 = Wo[(size_t)(k0+kl+3)*kV + v];
    #pragma unroll
    for (int b=0;b<kB;b++){
      float4 s4 = *(const float4*)&sf[b][kl];
      acc[b] += s4.x*w0 + s4.y*w1 + s4.z*w2 + s4.w*w3;
    }
  }
  #pragma unroll
  for (int b=0;b<kB;b++) partial[(size_t)(kq*kB+b)*kV + v] = acc[b];
}

__global__ __launch_bounds__(256) void k_out_sum(
    const float* __restrict__ partial, const float* __restrict__ bo,
    float* __restrict__ out)
{
  int v = blockIdx.x*256 + threadIdx.x;
  if (v >= kV) return;
  float bv = bo[v];
  #pragma unroll
  for (int b=0;b<kB;b++){
    float s = bv;
    #pragma unroll
    for (int q=0;q<4;q++) s += partial[(size_t)(q*kB+b)*kV + v];
    out[(size_t)b*kV + v] = s;
  }
}

extern "C" void kernel_launch(void* const* d_in, const int* in_sizes, int n_in,
                              void* d_out, int out_size, void* d_ws, size_t ws_size,
                              hipStream_t stream) {
  const float* emb   = (const float*)d_in[0];
  const float* Wx    = (const float*)d_in[1];
  const float* Wh    = (const float*)d_in[2];
  const float* bias  = (const float*)d_in[3];
  const float* Wb    = (const float*)d_in[4];
  const float* bbias = (const float*)d_in[5];
  const float* Wo    = (const float*)d_in[6];
  const float* bo    = (const float*)d_in[7];
  const int* t_idx   = (const int*)d_in[8];
  const int* f_idx   = (const int*)d_in[9];
  const int* exit_i  = (const int*)d_in[10];
  const int* steps   = (const int*)d_in[11];
  float* out = (float*)d_out;

  char* ws = (char*)d_ws;
  float* Xp  = (float*)ws; ws += (size_t)kB*kN*kH4*4;     // 33.55 MB, fragment-ordered X
  float* c2a = (float*)ws; ws += (size_t)kB*kN*kH*4;      // ping set (written at even s)
  float* h2a = (float*)ws; ws += (size_t)kB*kN*kH*4;
  char* setB = ws;
  float* c2b = (float*)ws; ws += (size_t)kB*kN*kH*4;      // pong set (written at odd s)
  float* h2b = (float*)ws; ws += (size_t)kB*kN*kH*4;
  u16* Wp_hi = (u16*)ws;  ws += (size_t)kH*kH4*2;
  u16* Wp_lo = (u16*)ws;  ws += (size_t)kH*kH4*2;
  float* pta = (float*)ws; ws += (size_t)kB*kN*4;
  float* pfa = (float*)ws; ws += (size_t)kB*kN*4;
  float* ptb = (float*)ws; ws += (size_t)kB*kN*4;
  float* pfb = (float*)ws; ws += (size_t)kB*kN*4;
  float* exf = (float*)ws; ws += (size_t)kB*2*kH*4;
  int* offsets = (int*)ws; ws += ((size_t)kB*(kN+1)*4 + 255) & ~(size_t)255;
  int* entries = (int*)ws; ws += (size_t)kB*2*kN*4;
  // aliases: emb-split + packed Wx live only until k_x_mfma completes,
  // before any write to the pong set (first written at s=1).
  u16* emb_hi = (u16*)setB;                                   // 4 MB
  u16* emb_lo = (u16*)(setB + (size_t)kB*kN*kH*2);            // 4 MB
  u16* Wxp_hi = (u16*)(setB + (size_t)kB*kN*kH*4);            // 512 KB
  u16* Wxp_lo = (u16*)(setB + (size_t)kB*kN*kH*4 + (size_t)kH*kH4*2);
  float* partial = Xp;  // reused after the step loop

  k_csr<<<kB, kN, 0, stream>>>(t_idx, f_idx, offsets, entries);
  k_split<<<2048, 256, 0, stream>>>(emb, emb_hi, emb_lo);
  k_pack<<<512, 64, 0, stream>>>(Wh, Wp_hi, Wp_lo);
  k_pack<<<512, 64, 0, stream>>>(Wx, Wxp_hi, Wxp_lo);
  k_x_mfma<<<256, 1024, 0, stream>>>(emb_hi, emb_lo, Wxp_hi, Wxp_lo, bias, Xp);

  for (int s = 0; s < kS; ++s){
    bool even = ((s & 1) == 0);
    k_fused<<<256, 1024, 0, stream>>>(
        Xp, Wp_hi, Wb, bbias, exit_i, steps, offsets, entries,
        even ? c2b : c2a, even ? h2b : h2a, even ? ptb : pta, even ? pfb : pfa,  // read (s-1)
        even ? c2a : c2b, even ? h2a : h2b, even ? pta : ptb, even ? pfa : pfb,  // write (s)
        exf, s);
  }

  k_out_part<<<500, 256, 0, stream>>>(exf, Wo, partial);
  k_out_sum<<<125, 256, 0, stream>>>(partial, bo, out);
}

// Round 6
// 1065.190 us; speedup vs baseline: 4.8304x; 1.0839x over previous
//
#include <hip/hip_runtime.h>
#include <hip/hip_bf16.h>

constexpr int kB  = 16;     // batch
constexpr int kN  = 512;    // nodes
constexpr int kH  = 256;    // hidden
constexpr int kH4 = 1024;   // 4*H
constexpr int kV  = 32000;  // vocab
constexpr int kS  = 48;     // MAX_STEPS (steps[b] <= 47)

typedef __attribute__((ext_vector_type(8))) short short8v;  // 8 bf16 = 4 VGPR
typedef __attribute__((ext_vector_type(4))) float f32x4;
typedef unsigned short u16;

__device__ __forceinline__ float sigm(float x){ return 1.f/(1.f+expf(-x)); }

__device__ __forceinline__ u16 f2bf(float f){
  __hip_bfloat16 h = __float2bfloat16(f);
  return __builtin_bit_cast(u16, h);
}
__device__ __forceinline__ float bf2f(u16 u){
  __hip_bfloat16 h = __builtin_bit_cast(__hip_bfloat16, u);
  return __bfloat162float(h);
}

// ---------------- CSR build (deterministic): atomics for counts/placement + bucket sort ----------------
__global__ void k_csr(const int* t_idx, const int* f_idx, int* offsets, int* entries){
  int b = blockIdx.x; int t = threadIdx.x; // 512 threads
  __shared__ int tl[kN], fl[kN], cnt[kN], pos[kN], ebuf[2*kN];
  tl[t] = t_idx[b*kN+t]; fl[t] = f_idx[b*kN+t];
  cnt[t] = 0;
  __syncthreads();
  atomicAdd(&cnt[tl[t]], 1);
  atomicAdd(&cnt[fl[t]], 1);
  __syncthreads();
  int myc = cnt[t];
  pos[t] = myc;
  __syncthreads();
  for (int off=1; off<kN; off<<=1){
    int v = pos[t];
    int add = (t>=off)? pos[t-off] : 0;
    __syncthreads();
    pos[t] = v + add;
    __syncthreads();
  }
  int excl = pos[t] - myc;
  offsets[b*(kN+1)+t] = excl;
  if (t==0) offsets[b*(kN+1)+kN] = 2*kN;
  __syncthreads();
  pos[t] = excl;
  __syncthreads();
  int p1 = atomicAdd(&pos[tl[t]], 1); ebuf[p1] = t;            // true branch
  int p2 = atomicAdd(&pos[fl[t]], 1); ebuf[p2] = t | (1<<16);  // false branch
  __syncthreads();
  for (int i = excl+1; i < excl+myc; ++i){      // sort own bucket: reference order
    int v = ebuf[i]; int j = i-1;
    while (j >= excl && ebuf[j] > v){ ebuf[j+1] = ebuf[j]; --j; }
    ebuf[j+1] = v;
  }
  __syncthreads();
  entries[b*2*kN + t]      = ebuf[t];
  entries[b*2*kN + kN + t] = ebuf[kN + t];
}

// ---------------- pack both weights into MFMA B-fragment order, split hi/lo (one launch) ----------------
// frag fi = ((kt*4 + wo)*16 + (g*4+j)); lane l supplies B[k][col] for
// k = kt*32 + (l>>4)*8 + jj, col = g*256 + wo*64 + j*16 + (l&15)
__global__ void k_pack2(const float* __restrict__ Wh, const float* __restrict__ Wx,
                        u16* __restrict__ Whh, u16* __restrict__ Whl,
                        u16* __restrict__ Wxh, u16* __restrict__ Wxl){
  int id = blockIdx.x; int l = threadIdx.x; // 1024 blocks x 64 threads
  const float* W = (id < 512) ? Wh : Wx;
  u16* ph = (id < 512) ? Whh : Wxh;
  u16* pl = (id < 512) ? Whl : Wxl;
  int fi = id & 511;
  int kt = fi >> 6; int wo = (fi>>4)&3; int cfl = fi & 15;
  int g = cfl>>2; int j = cfl&3;
  int col = g*kH + wo*64 + j*16 + (l&15);
  int kb = kt*32 + (l>>4)*8;
  size_t o = (size_t)fi*512 + (size_t)l*8;
  #pragma unroll
  for (int jj=0; jj<8; ++jj){
    float w = W[(size_t)(kb+jj)*kH4 + col];
    u16 hi = f2bf(w);
    u16 lo = f2bf(w - bf2f(hi));
    ph[o+jj] = hi; pl[o+jj] = lo;
  }
}

// ---------------- X = emb @ Wx + bias (MFMA, 3-term, emb split in-register), frag-order out ----------------
__global__ __launch_bounds__(1024) void k_x_mfma(
    const float* __restrict__ emb,
    const u16* __restrict__ Wxp_hi, const u16* __restrict__ Wxp_lo,
    const float* __restrict__ bias, float* __restrict__ Xp)
{
  int blk = blockIdx.x;
  int b = blk >> 4; int row0 = (blk & 15) * 32;
  int tid = threadIdx.x;
  int wn = tid >> 6, lane = tid & 63;
  int lrow = lane & 15, lk = lane >> 4;
  int ch = wn*16 + lrow;

  f32x4 acc[2][4];
  #pragma unroll
  for (int r=0;r<2;r++)
    #pragma unroll
    for (int g=0;g<4;g++){
      float bv = bias[g*kH + ch];
      acc[r][g] = (f32x4){bv,bv,bv,bv};
    }

  const float* eb_ = emb + ((size_t)b*kN + row0)*kH;
  int wo = wn >> 2, jj4 = wn & 3;
  for (int kt=0; kt<8; ++kt){
    short8v a_hi[2], a_lo[2];
    #pragma unroll
    for (int r=0;r<2;r++){
      size_t off = (size_t)(r*16+lrow)*kH + kt*32 + lk*8;
      float4 v0 = *(const float4*)(eb_ + off);
      float4 v1 = *(const float4*)(eb_ + off + 4);
      float vv[8] = {v0.x,v0.y,v0.z,v0.w,v1.x,v1.y,v1.z,v1.w};
      #pragma unroll
      for (int q=0;q<8;q++){
        u16 hi = f2bf(vv[q]);
        a_hi[r][q] = (short)hi;
        a_lo[r][q] = (short)f2bf(vv[q] - bf2f(hi));
      }
    }
    #pragma unroll
    for (int g=0; g<4; ++g){
      size_t fb = ((size_t)((kt*4+wo)*16 + g*4 + jj4))*512 + (size_t)lane*8;
      short8v bh = *(const short8v*)(Wxp_hi+fb);
      short8v bl = *(const short8v*)(Wxp_lo+fb);
      #pragma unroll
      for (int r=0;r<2;r++){
        acc[r][g] = __builtin_amdgcn_mfma_f32_16x16x32_bf16(a_hi[r], bh, acc[r][g], 0,0,0);
        acc[r][g] = __builtin_amdgcn_mfma_f32_16x16x32_bf16(a_lo[r], bh, acc[r][g], 0,0,0);
        acc[r][g] = __builtin_amdgcn_mfma_f32_16x16x32_bf16(a_hi[r], bl, acc[r][g], 0,0,0);
      }
    }
  }

  f32x4* xb = (f32x4*)(Xp + ((size_t)blk*16 + wn)*2048);
  #pragma unroll
  for (int r=0;r<2;r++)
    #pragma unroll
    for (int g=0;g<4;g++)
      xb[(r*4+g)*64 + lane] = acc[r][g];
}

// ---------------- fused step: gather(s-1) + LSTM/branch(s); 1-term MFMA, bf16 h state ----------------
// grid 256 blocks (16 ex x 16 rowblocks of 32), 1024 threads = 16 waves.
__global__ __launch_bounds__(1024) void k_fused(
    const float* __restrict__ Xp,
    const u16* __restrict__ Wp_hi,
    const float* __restrict__ Wb, const float* __restrict__ bb,
    const int* __restrict__ exit_idx, const int* __restrict__ steps,
    const int* __restrict__ offsets, const int* __restrict__ entries,
    const float* __restrict__ c2r, const u16* __restrict__ h2r,
    const float* __restrict__ ptr_, const float* __restrict__ pfr,
    float* __restrict__ c2w, u16* __restrict__ h2w,
    float* __restrict__ ptw, float* __restrict__ pfw,
    float* __restrict__ exf, int s)
{
  int blk = blockIdx.x;
  int b = blk >> 4;
  int st = steps[b];
  if (s > st) return;
  int row0 = (blk & 15) * 32;
  int tid = threadIdx.x;
  int wn = tid >> 6, lane = tid & 63;
  int lrow = lane & 15, lk = lane >> 4;
  int ch = wn*16 + lrow;
  int eb = exit_idx[b];
  bool fin = (s == st);

  __shared__ u16 hh_lds[32*256];   // bf16 h, XOR-swizzled rows
  __shared__ float c_lds[32][260]; // gathered c (padded stride)
  __shared__ float ip_lds[32];
  __shared__ float prs[16][32][2];

  // issue X loads early (independent of gather)
  f32x4 acc[2][4];
  {
    const f32x4* xb = (const f32x4*)(Xp + ((size_t)blk*16 + wn)*2048);
    #pragma unroll
    for (int r=0;r<2;r++)
      #pragma unroll
      for (int g=0;g<4;g++)
        acc[r][g] = xb[(r*4+g)*64 + lane];
  }

  // ---- Phase A: gather previous step's outputs into LDS (or init at s==0) ----
  if (s == 0){
    for (int i = tid; i < 32*256; i += 1024) hh_lds[i] = 0;
    for (int i = tid; i < 32*260; i += 1024) (&c_lds[0][0])[i] = 0.f;
    if (tid < 32) ip_lds[tid] = (row0 + tid == 0) ? 1.f : 0.f;
  } else {
    const float* c2rb = c2r + (size_t)b*kN*kH;
    const u16*   h2rb = h2r + (size_t)b*kN*kH;
    const int*   ebL  = entries + b*2*kN;
    const float* ptb_ = ptr_ + b*kN;
    const float* pfb_ = pfr  + b*kN;
    #pragma unroll
    for (int mi = 0; mi < 2; ++mi){
      int mloc = wn*2 + mi;
      int m = row0 + mloc;
      int start = offsets[b*(kN+1)+m], end = offsets[b*(kN+1)+m+1];
      float4 aC = {0.f,0.f,0.f,0.f}, aH = {0.f,0.f,0.f,0.f};
      float aP = 0.f;
      for (int e = start; e < end; e += 2){        // batch-2 pipelined, deterministic order
        int ent0 = ebL[e];
        bool ok1 = (e+1 < end);
        int ent1 = ebL[ok1 ? e+1 : e];
        int src0 = ent0 & 0xFFFF, src1 = ent1 & 0xFFFF;
        float pv0 = (ent0>>16) ? pfb_[src0] : ptb_[src0];
        float pv1 = (ent1>>16) ? pfb_[src1] : ptb_[src1];
        pv1 = ok1 ? pv1 : 0.f;
        float4  cv0 = *(const float4*)&c2rb[(size_t)src0*kH + lane*4];
        float4  cv1 = *(const float4*)&c2rb[(size_t)src1*kH + lane*4];
        ushort4 hv0 = *(const ushort4*)&h2rb[(size_t)src0*kH + lane*4];
        ushort4 hv1 = *(const ushort4*)&h2rb[(size_t)src1*kH + lane*4];
        aP += pv0 + pv1;
        aC.x += pv0*cv0.x + pv1*cv1.x;
        aC.y += pv0*cv0.y + pv1*cv1.y;
        aC.z += pv0*cv0.z + pv1*cv1.z;
        aC.w += pv0*cv0.w + pv1*cv1.w;
        aH.x += pv0*bf2f(hv0.x) + pv1*bf2f(hv1.x);
        aH.y += pv0*bf2f(hv0.y) + pv1*bf2f(hv1.y);
        aH.z += pv0*bf2f(hv0.z) + pv1*bf2f(hv1.z);
        aH.w += pv0*bf2f(hv0.w) + pv1*bf2f(hv1.w);
      }
      float inv = 1.f/(aP + 1e-7f);
      float oc[4] = {aC.x*inv, aC.y*inv, aC.z*inv, aC.w*inv};
      float oh[4] = {aH.x*inv, aH.y*inv, aH.z*inv, aH.w*inv};
      if (fin){
        if (m == eb){
          *(float4*)&exf[b*2*kH + lane*4]      = *(float4*)oc;
          *(float4*)&exf[b*2*kH + kH + lane*4] = *(float4*)oh;
        }
      } else {
        *(float4*)&c_lds[mloc][lane*4] = *(float4*)oc;
        ushort4 hh4;
        u16* hhp = (u16*)&hh4;
        #pragma unroll
        for (int q=0;q<4;q++) hhp[q] = f2bf(oh[q]);
        int bo2 = (mloc*512 + lane*8) ^ ((mloc&7)<<4);
        *(ushort4*)((char*)hh_lds + bo2) = hh4;
        if (lane == 0) ip_lds[mloc] = aP;
      }
    }
  }
  if (fin) return;
  __syncthreads();

  // ---- Phase B: MFMA K-loop (1-term: bf16 h x bf16-hi W), A from swizzled LDS ----
  int wo = wn >> 2, jj4 = wn & 3;
  for (int kt=0; kt<8; ++kt){
    short8v a[2];
    #pragma unroll
    for (int r=0;r<2;r++){
      int row = r*16 + lrow;
      int bo2 = (row*512 + kt*64 + lk*16) ^ ((row&7)<<4);
      a[r] = *(const short8v*)((char*)hh_lds + bo2);
    }
    #pragma unroll
    for (int g=0; g<4; ++g){
      size_t fb = ((size_t)((kt*4+wo)*16 + g*4 + jj4))*512 + (size_t)lane*8;
      short8v bh = *(const short8v*)(Wp_hi+fb);
      #pragma unroll
      for (int r=0;r<2;r++)
        acc[r][g] = __builtin_amdgcn_mfma_f32_16x16x32_bf16(a[r], bh, acc[r][g], 0,0,0);
    }
  }

  // ---- epilogue: gates, exit override, branch-logit partials ----
  float wbc0 = Wb[ch*2+0],      wbc1 = Wb[ch*2+1];
  float wbh0 = Wb[(kH+ch)*2+0], wbh1 = Wb[(kH+ch)*2+1];
  float pr0[8], pr1[8];

  #pragma unroll
  for (int r=0;r<2;r++)
    #pragma unroll
    for (int reg=0;reg<4;reg++){
      int rloc = r*16 + lk*4 + reg;
      int row = row0 + rloc;
      float zi = acc[r][0][reg];
      float zf = acc[r][1][reg];
      float zg = acc[r][2][reg];
      float zo = acc[r][3][reg];
      float cp = c_lds[rloc][ch];
      float c2v = sigm(zf)*cp + sigm(zi)*tanhf(zg);
      float h2v = sigm(zo)*tanhf(c2v);
      if (row == eb){
        int bo2 = (rloc*512 + ch*2) ^ ((rloc&7)<<4);
        c2v = cp;
        h2v = bf2f(*(const u16*)((const char*)hh_lds + bo2));
      }
      size_t gb = ((size_t)b*kN + row)*kH + ch;
      c2w[gb] = c2v;
      h2w[gb] = f2bf(h2v);
      int pi = r*4+reg;
      pr0[pi] = c2v*wbc0 + h2v*wbh0;
      pr1[pi] = c2v*wbc1 + h2v*wbh1;
    }

  #pragma unroll
  for (int off=1; off<16; off<<=1){
    #pragma unroll
    for (int i=0;i<8;i++){
      pr0[i] += __shfl_xor(pr0[i], off);
      pr1[i] += __shfl_xor(pr1[i], off);
    }
  }
  if (lrow == 0){
    #pragma unroll
    for (int r=0;r<2;r++)
      #pragma unroll
      for (int reg=0;reg<4;reg++){
        int lr = r*16 + lk*4 + reg;
        prs[wn][lr][0] = pr0[r*4+reg];
        prs[wn][lr][1] = pr1[r*4+reg];
      }
  }
  __syncthreads();
  if (tid < 32){
    int row = row0 + tid;
    float u0 = bb[0], u1 = bb[1];
    #pragma unroll
    for (int w=0;w<16;w++){ u0 += prs[w][tid][0]; u1 += prs[w][tid][1]; }
    float mx = fmaxf(u0,u1);
    float e0 = expf(u0-mx), e1 = expf(u1-mx);
    float inv = 1.f/(e0+e1);
    float ipv = ip_lds[tid];
    ptw[b*kN+row] = (e0*inv)*ipv;
    pfw[b*kN+row] = (e1*inv)*ipv;
  }
}

// ---------------- final: logits = exitstate @ Wo + bo  (split-K) ----------------
__global__ __launch_bounds__(256) void k_out_part(
    const float* __restrict__ exf, const float* __restrict__ Wo,
    float* __restrict__ partial)
{
  int kq = blockIdx.x / 125;
  int vt = blockIdx.x % 125;
  int t = threadIdx.x;
  __shared__ float sf[kB][128];
  for (int i = t; i < kB*128; i += 256){
    int b = i >> 7; int kl = i & 127;
    sf[b][kl] = exf[b*2*kH + kq*128 + kl];
  }
  __syncthreads();
  int v = vt*256 + t;
  float acc[kB];
  #pragma unroll
  for (int b=0;b<kB;b++) acc[b] = 0.f;
  int k0 = kq*128;
  for (int kl=0; kl<128; kl+=4){
    float w0 = Wo[(size_t)(k0+kl+0)*kV + v];
    float w1 = Wo[(size_t)(k0+kl+1)*kV + v];
    float w2 = Wo[(size_t)(k0+kl+2)*kV + v];
    float w3 = Wo[(size_t)(k0+kl+3)*kV + v];
    #pragma unroll
    for (int b=0;b<kB;b++){
      float4 s4 = *(const float4*)&sf[b][kl];
      acc[b] += s4.x*w0 + s4.y*w1 + s4.z*w2 + s4.w*w3;
    }
  }
  #pragma unroll
  for (int b=0;b<kB;b++) partial[(size_t)(kq*kB+b)*kV + v] = acc[b];
}

__global__ __launch_bounds__(256) void k_out_sum(
    const float* __restrict__ partial, const float* __restrict__ bo,
    float* __restrict__ out)
{
  int v = blockIdx.x*256 + threadIdx.x;
  if (v >= kV) return;
  float bv = bo[v];
  #pragma unroll
  for (int b=0;b<kB;b++){
    float s = bv;
    #pragma unroll
    for (int q=0;q<4;q++) s += partial[(size_t)(q*kB+b)*kV + v];
    out[(size_t)b*kV + v] = s;
  }
}

extern "C" void kernel_launch(void* const* d_in, const int* in_sizes, int n_in,
                              void* d_out, int out_size, void* d_ws, size_t ws_size,
                              hipStream_t stream) {
  const float* emb   = (const float*)d_in[0];
  const float* Wx    = (const float*)d_in[1];
  const float* Wh    = (const float*)d_in[2];
  const float* bias  = (const float*)d_in[3];
  const float* Wb    = (const float*)d_in[4];
  const float* bbias = (const float*)d_in[5];
  const float* Wo    = (const float*)d_in[6];
  const float* bo    = (const float*)d_in[7];
  const int* t_idx   = (const int*)d_in[8];
  const int* f_idx   = (const int*)d_in[9];
  const int* exit_i  = (const int*)d_in[10];
  const int* steps   = (const int*)d_in[11];
  float* out = (float*)d_out;

  char* ws = (char*)d_ws;
  float* Xp  = (float*)ws; ws += (size_t)kB*kN*kH4*4;     // 33.55 MB, fragment-ordered X
  float* c2a = (float*)ws; ws += (size_t)kB*kN*kH*4;      // ping (written at even s)
  float* c2b = (float*)ws; ws += (size_t)kB*kN*kH*4;      // pong (written at odd s)
  u16* h2a = (u16*)ws;    ws += (size_t)kB*kN*kH*2;       // bf16 h state
  u16* h2b = (u16*)ws;    ws += (size_t)kB*kN*kH*2;
  u16* Wp_hi  = (u16*)ws; ws += (size_t)kH*kH4*2;
  u16* Wp_lo  = (u16*)ws; ws += (size_t)kH*kH4*2;         // packed but unused in step loop
  u16* Wxp_hi = (u16*)ws; ws += (size_t)kH*kH4*2;
  u16* Wxp_lo = (u16*)ws; ws += (size_t)kH*kH4*2;
  float* pta = (float*)ws; ws += (size_t)kB*kN*4;
  float* pfa = (float*)ws; ws += (size_t)kB*kN*4;
  float* ptb = (float*)ws; ws += (size_t)kB*kN*4;
  float* pfb = (float*)ws; ws += (size_t)kB*kN*4;
  float* exf = (float*)ws; ws += (size_t)kB*2*kH*4;
  int* offsets = (int*)ws; ws += ((size_t)kB*(kN+1)*4 + 255) & ~(size_t)255;
  int* entries = (int*)ws; ws += (size_t)kB*2*kN*4;
  float* partial = Xp;  // reused after the step loop

  k_csr<<<kB, kN, 0, stream>>>(t_idx, f_idx, offsets, entries);
  k_pack2<<<1024, 64, 0, stream>>>(Wh, Wx, Wp_hi, Wp_lo, Wxp_hi, Wxp_lo);
  k_x_mfma<<<256, 1024, 0, stream>>>(emb, Wxp_hi, Wxp_lo, bias, Xp);

  for (int s = 0; s < kS; ++s){
    bool even = ((s & 1) == 0);
    k_fused<<<256, 1024, 0, stream>>>(
        Xp, Wp_hi, Wb, bbias, exit_i, steps, offsets, entries,
        even ? c2b : c2a, even ? h2b : h2a, even ? ptb : pta, even ? pfb : pfa,  // read (s-1)
        even ? c2a : c2b, even ? h2a : h2b, even ? pta : ptb, even ? pfa : pfb,  // write (s)
        exf, s);
  }

  k_out_part<<<500, 256, 0, stream>>>(exf, Wo, partial);
  k_out_sum<<<125, 256, 0, stream>>>(partial, bo, out);
}